// Round 1
// baseline (588.098 us; speedup 1.0000x reference)
//
#include <hip/hip_runtime.h>
#include <hip/hip_bf16.h>
#include <math.h>

#define DEV __device__ __forceinline__

constexpr int BATCH = 4096;
constexpr int NBA = 512;   // pool/minmax blocks
constexpr int NBB = 512;   // conv1-stats blocks (8 img each)
constexpr int NBC = 2048;  // fused conv blocks (2 img each)
constexpr int NBE = 256;   // fc1 blocks (16 img each)

// workspace layout (float offsets)
constexpr size_t OFF_POOLED = 0;                            // 4096*196
constexpr size_t OFF_Y2P = OFF_POOLED + (size_t)BATCH*196;  // 4096*400 (pooled conv2 out)
constexpr size_t OFF_H3  = OFF_Y2P + (size_t)BATCH*400;     // 4096*128 (fc1 post-relu)
constexpr size_t OFF_W1  = OFF_H3 + (size_t)BATCH*128;      // 576
constexpr size_t OFF_W2  = OFF_W1 + 576;                    // 9216, layout [(icg*9+ky*3+kx)*64 + sub*16 + oc]
constexpr size_t OFF_W3  = OFF_W2 + 9216;                   // 51200, layout [k*128+oc]
constexpr size_t OFF_W4  = OFF_W3 + 51200;                  // 1280, natural [oc*128+k]
constexpr size_t OFF_WSC = OFF_W4 + 1280;                   // 4 layer scales
constexpr size_t OFF_MMA = OFF_WSC + 4;                     // NBA*2 pooled min/max partials
constexpr size_t OFF_ST1 = OFF_MMA + (size_t)NBA*2;         // 64*NBB*4 conv1 channel stats partials
constexpr size_t OFF_BN1 = OFF_ST1 + (size_t)64*NBB*4;      // 64*4 {mean, sd, tmin, tmax}
constexpr size_t OFF_ST2 = OFF_BN1 + 256;                   // 16*NBC*4
constexpr size_t OFF_BN2 = OFF_ST2 + (size_t)16*NBC*4;      // 16*4
constexpr size_t OFF_MME = OFF_BN2 + 64;                    // NBE*2 fc1 min/max partials
constexpr size_t WS_FLOATS = OFF_MME + (size_t)NBE*2;       // ~3.23M floats ~ 13 MB

struct InPtrs {
  const float* x;
  const float* sc[4];
  const float* sg[4];
  const float* on[4];
  const float* ze[4];
  const int* qb;
};

DEV unsigned fenc(float f){ unsigned u=__float_as_uint(f); return (u&0x80000000u)? ~u : (u|0x80000000u); }
DEV float fdec(unsigned e){ return __uint_as_float((e&0x80000000u)? (e&0x7fffffffu) : ~e); }

DEV float blk_min(float v, float* red, int t){
  red[t]=v; __syncthreads();
  for (int s=128;s>0;s>>=1){ if(t<s) red[t]=fminf(red[t],red[t+s]); __syncthreads(); }
  float r=red[0]; __syncthreads();
  return r;
}
DEV float blk_max(float v, float* red, int t){
  red[t]=v; __syncthreads();
  for (int s=128;s>0;s>>=1){ if(t<s) red[t]=fmaxf(red[t],red[t+s]); __syncthreads(); }
  float r=red[0]; __syncthreads();
  return r;
}
DEV float blk_sum(float v, float* red, int t){
  red[t]=v; __syncthreads();
  for (int s=128;s>0;s>>=1){ if(t<s) red[t]+=red[t+s]; __syncthreads(); }
  float r=red[0]; __syncthreads();
  return r;
}

DEV void loadrow16(const float* p, float* r){
  const float4* q=(const float4*)p;
  float4 a=q[0],b=q[1],c=q[2],d=q[3];
  r[0]=a.x;r[1]=a.y;r[2]=a.z;r[3]=a.w;
  r[4]=b.x;r[5]=b.y;r[6]=b.z;r[7]=b.w;
  r[8]=c.x;r[9]=c.y;r[10]=c.z;r[11]=c.w;
  r[12]=d.x;r[13]=d.y;r[14]=d.z;r[15]=d.w;
}

// one 12-wide conv1 output row -> channel stats (v = conv/scale1w)
DEV void c1row_stat(const float* ra,const float* rb,const float* rc,const float* w,
                    float inv_s1w,float& sum,float& sq,float& vmn,float& vmx){
  #pragma unroll
  for (int x=0;x<12;++x){
    float a=ra[x]*w[0];
    a=fmaf(ra[x+1],w[1],a); a=fmaf(ra[x+2],w[2],a);
    a=fmaf(rb[x],w[3],a);   a=fmaf(rb[x+1],w[4],a); a=fmaf(rb[x+2],w[5],a);
    a=fmaf(rc[x],w[6],a);   a=fmaf(rc[x+1],w[7],a); a=fmaf(rc[x+2],w[8],a);
    float v=a*inv_s1w;
    sum+=v; sq=fmaf(v,v,sq); vmn=fminf(vmn,v); vmx=fmaxf(vmx,v);
  }
}

// one 12-wide conv1 row -> bn+relu+quant -> packed u8 code in LDS
DEV void c1row_q(const float* ra,const float* rb,const float* rc,const float* w,
                 float Ac,float Bc,float inv_s2,float lvf,int y,int c,unsigned char* a1b){
  const int icg=c>>2, sub=c&3;
  #pragma unroll
  for (int x=0;x<12;++x){
    float a=ra[x]*w[0];
    a=fmaf(ra[x+1],w[1],a); a=fmaf(ra[x+2],w[2],a);
    a=fmaf(rb[x],w[3],a);   a=fmaf(rb[x+1],w[4],a); a=fmaf(rb[x+2],w[5],a);
    a=fmaf(rc[x],w[6],a);   a=fmaf(rc[x+1],w[7],a); a=fmaf(rc[x+2],w[8],a);
    float bnv=fmaf(a,Ac,Bc);
    float r=fmaxf(bnv,0.f);
    float irf=fminf(rintf(r*inv_s2),lvf);
    a1b[((icg*144+y*12+x)<<2)+sub]=(unsigned char)irf;
  }
}

DEV void fma16(float cs, const float* wp, float* acc){
  const float4* w4=(const float4*)wp;
  float4 a=w4[0],b=w4[1],c=w4[2],d=w4[3];
  acc[0]=fmaf(cs,a.x,acc[0]);  acc[1]=fmaf(cs,a.y,acc[1]);  acc[2]=fmaf(cs,a.z,acc[2]);  acc[3]=fmaf(cs,a.w,acc[3]);
  acc[4]=fmaf(cs,b.x,acc[4]);  acc[5]=fmaf(cs,b.y,acc[5]);  acc[6]=fmaf(cs,b.z,acc[6]);  acc[7]=fmaf(cs,b.w,acc[7]);
  acc[8]=fmaf(cs,c.x,acc[8]);  acc[9]=fmaf(cs,c.y,acc[9]);  acc[10]=fmaf(cs,c.z,acc[10]); acc[11]=fmaf(cs,c.w,acc[11]);
  acc[12]=fmaf(cs,d.x,acc[12]); acc[13]=fmaf(cs,d.y,acc[13]); acc[14]=fmaf(cs,d.z,acc[14]); acc[15]=fmaf(cs,d.w,acc[15]);
}

// ---------------- KW: blended weights via exact radix-select top-k of |scores| ----------------
__global__ __launch_bounds__(256) void kw_kernel(InPtrs in, float* __restrict__ ws){
  const int t=threadIdx.x;
  const int L=blockIdx.x;
  const int Ns[4]={576,9216,51200,1280};
  const int fans[4]={9,576,400,128};
  const int N=Ns[L];
  const int K=N>>1;
  const float* sc=in.sc[L];
  __shared__ int hist[4096];
  __shared__ int csum[256];
  __shared__ int sh2[2];

  auto find4096=[&](int kk){
    int local=0;
    #pragma unroll
    for (int j=0;j<16;++j) local+=hist[t*16+j];
    csum[t]=local; __syncthreads();
    if (t==0){
      int cum=0;
      for (int ci=255; ci>=0; --ci){
        int cs2=csum[ci];
        if (cum+cs2>=kk){
          int c2=cum;
          for (int bb=ci*16+15; bb>=ci*16; --bb){
            c2+=hist[bb];
            if (c2>=kk){ sh2[0]=bb; sh2[1]=kk-(c2-hist[bb]); break; }
          }
          break;
        }
        cum+=cs2;
      }
    }
    __syncthreads();
    int b=sh2[0], r=sh2[1];
    __syncthreads();
    return make_int2(b,r);
  };

  // pass 1: top 12 bits
  for (int i=t;i<4096;i+=256) hist[i]=0;
  __syncthreads();
  for (int i=t;i<N;i+=256){ unsigned u=__float_as_uint(sc[i])&0x7fffffffu; atomicAdd(&hist[u>>19],1); }
  __syncthreads();
  int2 f1=find4096(K);
  const int b0=f1.x; const int r1=f1.y;
  // pass 2: mid 12 bits
  for (int i=t;i<4096;i+=256) hist[i]=0;
  __syncthreads();
  for (int i=t;i<N;i+=256){
    unsigned u=__float_as_uint(sc[i])&0x7fffffffu;
    if ((int)(u>>19)==b0) atomicAdd(&hist[(u>>7)&0xfffu],1);
  }
  __syncthreads();
  int2 f2=find4096(r1);
  const int b1=f2.x; const int r2=f2.y;
  const unsigned pre=((unsigned)b0<<12)|(unsigned)b1;
  // pass 3: low 7 bits
  if (t<128) hist[t]=0;
  __syncthreads();
  for (int i=t;i<N;i+=256){
    unsigned u=__float_as_uint(sc[i])&0x7fffffffu;
    if ((u>>7)==pre) atomicAdd(&hist[u&127u],1);
  }
  __syncthreads();
  if (t==0){
    int cum=0;
    for (int bb=127; bb>=0; --bb){ cum+=hist[bb]; if (cum>=r2){ sh2[0]=bb; break; } }
  }
  __syncthreads();
  const unsigned T=(pre<<7)|(unsigned)sh2[0];  // bits of k-th largest |score|

  // write blended weights (layer-specific layout) + scale = mean(hw_one)*sqrt(fan)/2
  const float* sg=in.sg[L]; const float* on=in.on[L]; const float* ze=in.ze[L];
  float* wout=ws+(L==0?OFF_W1: L==1?OFF_W2 : L==2?OFF_W3 : OFF_W4);
  double lsum=0.0;
  for (int i=t;i<N;i+=256){
    unsigned u=__float_as_uint(sc[i])&0x7fffffffu;
    float w=sg[i]*((u>=T)? on[i] : ze[i]);
    int o;
    if (L==0) o=i;
    else if (L==1){ int oc=i/576; int r=i-oc*576; int ic=r/9; int rr=r-ic*9;
                    o=((ic>>2)*9+rr)*64+(ic&3)*16+oc; }
    else if (L==2){ int oc=i/400; int kk=i-oc*400; o=kk*128+oc; }
    else o=i;
    wout[o]=w;
    lsum+=(double)on[i];
  }
  __shared__ double dred[256];
  dred[t]=lsum; __syncthreads();
  for (int s=128;s>0;s>>=1){ if(t<s) dred[t]+=dred[t+s]; __syncthreads(); }
  if (t==0) ws[OFF_WSC+L]=(float)((dred[0]/(double)N)*sqrt((double)fans[L])*0.5);
}

// ---------------- KA: 2x2 maxpool + pooled min/max partials ----------------
__global__ __launch_bounds__(256) void ka_kernel(InPtrs in, float* __restrict__ ws){
  const int t=threadIdx.x, blk=blockIdx.x;
  const float* x=in.x;
  float* pooled=ws+OFF_POOLED;
  float lmn=3.4e38f, lmx=-3.4e38f;
  for (int p=blk*256+t; p<BATCH*196; p+=NBA*256){
    int b=p/196, r=p-b*196;
    int oy=r/14, ox=r-oy*14;
    const float* px=x+b*784+oy*56+ox*2;
    float m=fmaxf(fmaxf(px[0],px[1]),fmaxf(px[28],px[29]));
    pooled[p]=m;
    lmn=fminf(lmn,m); lmx=fmaxf(lmx,m);
  }
  __shared__ float red[256];
  float bmn=blk_min(lmn,red,t);
  float bmx=blk_max(lmx,red,t);
  if (t==0){ ws[OFF_MMA+blk*2]=bmn; ws[OFF_MMA+blk*2+1]=bmx; }
}

// ---------------- KB: conv1 (recomputed) -> per-channel BN1 stats partials ----------------
__global__ __launch_bounds__(256) void kb_kernel(InPtrs in, const float* __restrict__ wsr, float* __restrict__ wsw){
  const int t=threadIdx.x, blk=blockIdx.x;
  __shared__ __align__(16) float qxs[224];
  __shared__ float red[256];
  const float* pooled=wsr+OFF_POOLED;
  float lmn=3.4e38f,lmx=-3.4e38f;
  for (int i=t;i<NBA;i+=256){ lmn=fminf(lmn,wsr[OFF_MMA+2*i]); lmx=fmaxf(lmx,wsr[OFF_MMA+2*i+1]); }
  const float mn0=blk_min(lmn,red,t);
  const float mx0=blk_max(lmx,red,t);
  const float lvf=(float)((1<<in.qb[0])-1);
  const float s0=(mx0-mn0)/lvf;
  const float inv_s0=1.0f/s0;
  const float zp0=floorf(mn0/s0);
  const float inv_s1w=1.0f/wsr[OFF_WSC+0];
  const int c=t>>2, q=t&3;
  float w[9];
  #pragma unroll
  for (int j=0;j<9;++j) w[j]=wsr[OFF_W1+c*9+j];
  float sum=0.f,sq=0.f,vmn=3.4e38f,vmx=-3.4e38f;
  #pragma unroll 1
  for (int ii=0;ii<8;++ii){
    const int b=blk*8+ii;
    __syncthreads();
    for (int i=t;i<224;i+=256){
      int row=i>>4,col=i&15;
      float v=0.f;
      if (col<14){ float xx=pooled[b*196+row*14+col]; v=(rintf((xx-mn0)*inv_s0)+zp0)*s0; }
      qxs[i]=v;
    }
    __syncthreads();
    float rA[16],rB[16],rC[16];
    const int y0=q*3;
    loadrow16(qxs+y0*16,rA);
    loadrow16(qxs+(y0+1)*16,rB);
    loadrow16(qxs+(y0+2)*16,rC); c1row_stat(rA,rB,rC,w,inv_s1w,sum,sq,vmn,vmx);
    loadrow16(qxs+(y0+3)*16,rA); c1row_stat(rB,rC,rA,w,inv_s1w,sum,sq,vmn,vmx);
    loadrow16(qxs+(y0+4)*16,rB); c1row_stat(rC,rA,rB,w,inv_s1w,sum,sq,vmn,vmx);
  }
  #pragma unroll
  for (int d=1;d<4;d<<=1){
    sum+=__shfl_xor(sum,d);
    sq +=__shfl_xor(sq,d);
    vmn=fminf(vmn,__shfl_xor(vmn,d));
    vmx=fmaxf(vmx,__shfl_xor(vmx,d));
  }
  if (q==0){
    float* p=wsw+OFF_ST1+((size_t)c*NBB+blk)*4;
    p[0]=sum; p[1]=sq; p[2]=vmn; p[3]=vmx;
  }
}

// ---------------- kstat: per-channel partial reduce -> {mean, sd, tmin, tmax} ----------------
__global__ __launch_bounds__(256) void kstat_kernel(const float* __restrict__ wsr, float* __restrict__ wsw,
                                                    unsigned long long inoff, int nparts, float Nf,
                                                    unsigned long long outoff){
  const int c=blockIdx.x, t=threadIdx.x;
  __shared__ float red[256];
  const float* p=wsr+inoff+(size_t)c*nparts*4;
  float sum=0.f,sq=0.f,mn=3.4e38f,mx=-3.4e38f;
  for (int i=t;i<nparts;i+=256){
    sum+=p[i*4]; sq+=p[i*4+1];
    mn=fminf(mn,p[i*4+2]); mx=fmaxf(mx,p[i*4+3]);
  }
  float S=blk_sum(sum,red,t);
  float Q=blk_sum(sq,red,t);
  float MN=blk_min(mn,red,t);
  float MX=blk_max(mx,red,t);
  if (t==0){
    float mean=S/Nf;
    float var=fmaxf(Q/Nf-mean*mean,0.f);
    float sd=sqrtf(var+1e-5f);
    float* o=wsw+outoff+c*4;
    o[0]=mean; o[1]=sd; o[2]=(MN-mean)/sd; o[3]=(MX-mean)/sd;
  }
}

// ---------------- KC: fused conv1->bn1/relu/quant->conv2->pool + BN2 stats partials ----------------
__global__ __launch_bounds__(256) void kc_kernel(InPtrs in, const float* __restrict__ wsr, float* __restrict__ wsw){
  const int t=threadIdx.x, blk=blockIdx.x;
  __shared__ __align__(16) float qxs[448];      // 2 img x 14x16 quantized input
  __shared__ unsigned sa1[4608];                // 2 img x [icg][12x12] packed u8 codes (4 ic / u32)
  __shared__ float c2s[3200];                   // 2 img x [oc][10x10] conv2 out
  __shared__ float sA[64], sB[64];
  __shared__ float red[256];
  __shared__ float stsum[16], stsq[16];
  __shared__ unsigned stmn[16], stmx[16];
  const float* pooled=wsr+OFF_POOLED;
  float lmn=3.4e38f,lmx=-3.4e38f;
  for (int i=t;i<NBA;i+=256){ lmn=fminf(lmn,wsr[OFF_MMA+2*i]); lmx=fmaxf(lmx,wsr[OFF_MMA+2*i+1]); }
  const float mn0=blk_min(lmn,red,t);
  const float mx0=blk_max(lmx,red,t);
  const float lvf=(float)((1<<in.qb[0])-1);
  const float s0=(mx0-mn0)/lvf, inv_s0=1.0f/s0, zp0=floorf(mn0/s0);
  const float s1w=wsr[OFF_WSC+0], s2w=wsr[OFF_WSC+1];
  if (t<64){
    float m=wsr[OFF_BN1+t*4], sd=wsr[OFF_BN1+t*4+1];
    sA[t]=1.0f/(s1w*sd);
    sB[t]=-m/sd;
  }
  float tmn=(t<64)?wsr[OFF_BN1+t*4+2]:3.4e38f;
  float tmx=(t<64)?wsr[OFF_BN1+t*4+3]:-3.4e38f;
  const float rmn=blk_min(tmn,red,t);
  const float rmx=blk_max(tmx,red,t);
  const float s2=(fmaxf(rmx,0.f)-fmaxf(rmn,0.f))/lvf;
  const float inv_s2=1.0f/s2;
  const float g2=s2/s2w;
  if (t<16){ stsum[t]=0.f; stsq[t]=0.f; stmn[t]=0xFFFFFFFFu; stmx[t]=0u; }
  const int b0=blk*2;
  __syncthreads();

  // quantized pooled input, both images
  for (int i=t;i<448;i+=256){
    int img=(i>=224), r=i-img*224;
    int row=r>>4, col=r&15;
    float v=0.f;
    if (col<14){ float xx=pooled[(b0+img)*196+row*14+col]; v=(rintf((xx-mn0)*inv_s0)+zp0)*s0; }
    qxs[i]=v;
  }
  __syncthreads();

  // conv1 + bn + relu + quant -> packed codes
  {
    const int img=t>>7, lp=t&127;
    const int c=lp>>1, q=lp&1;
    const float Ac=sA[c], Bc=sB[c];
    float w[9];
    #pragma unroll
    for (int j=0;j<9;++j) w[j]=wsr[OFF_W1+c*9+j];
    const float* qx=qxs+img*224;
    unsigned char* a1b=(unsigned char*)(sa1+img*2304);
    float rA[16],rB[16],rC[16];
    const int y0=q*6;
    loadrow16(qx+y0*16,rA);
    loadrow16(qx+(y0+1)*16,rB);
    loadrow16(qx+(y0+2)*16,rC); c1row_q(rA,rB,rC,w,Ac,Bc,inv_s2,lvf,y0+0,c,a1b);
    loadrow16(qx+(y0+3)*16,rA); c1row_q(rB,rC,rA,w,Ac,Bc,inv_s2,lvf,y0+1,c,a1b);
    loadrow16(qx+(y0+4)*16,rB); c1row_q(rC,rA,rB,w,Ac,Bc,inv_s2,lvf,y0+2,c,a1b);
    loadrow16(qx+(y0+5)*16,rC); c1row_q(rA,rB,rC,w,Ac,Bc,inv_s2,lvf,y0+3,c,a1b);
    loadrow16(qx+(y0+6)*16,rA); c1row_q(rB,rC,rA,w,Ac,Bc,inv_s2,lvf,y0+4,c,a1b);
    loadrow16(qx+(y0+7)*16,rB); c1row_q(rC,rA,rB,w,Ac,Bc,inv_s2,lvf,y0+5,c,a1b);
  }
  __syncthreads();

  // conv2: lane = spatial position, acc over 16 oc; weights wave-uniform
  {
    const int img=t>>7, lp=t&127;
    const bool act=lp<100;
    const int p=act?lp:0;
    const int py=p/10, px=p-py*10;
    const unsigned* a1w=sa1+img*2304;
    const float* w2=wsr+OFF_W2;
    float acc[16];
    #pragma unroll
    for (int j=0;j<16;++j) acc[j]=0.f;
    const int off=py*12+px;
    #pragma unroll 1
    for (int icg=0;icg<16;++icg){
      const unsigned* bs=a1w+icg*144+off;
      const float* wb=w2+icg*576;
      #pragma unroll
      for (int ky=0;ky<3;++ky){
        #pragma unroll
        for (int kx=0;kx<3;++kx){
          unsigned code=bs[ky*12+kx];
          const float* wp=wb+(ky*3+kx)*64;
          fma16((float)(code&255u),       wp,    acc);
          fma16((float)((code>>8)&255u),  wp+16, acc);
          fma16((float)((code>>16)&255u), wp+32, acc);
          fma16((float)(code>>24),        wp+48, acc);
        }
      }
    }
    if (act){
      #pragma unroll
      for (int j=0;j<16;++j) c2s[img*1600+j*100+lp]=acc[j]*g2;
    }
  }
  __syncthreads();

  // 2x2 maxpool + per-channel stats
  for (int i=t;i<800;i+=256){
    int img=(i>=400), r=i-img*400;
    int ch=r/25, pp=r-ch*25;
    int py=pp/5, px=pp-py*5;
    const float* cc=c2s+img*1600+ch*100;
    int base=py*20+px*2;
    float v=fmaxf(fmaxf(cc[base],cc[base+1]),fmaxf(cc[base+10],cc[base+11]));
    wsw[OFF_Y2P+(size_t)(b0+img)*400+r]=v;
    atomicAdd(&stsum[ch],v);
    atomicAdd(&stsq[ch],v*v);
    atomicMin(&stmn[ch],fenc(v));
    atomicMax(&stmx[ch],fenc(v));
  }
  __syncthreads();
  if (t<16){
    float* p=wsw+OFF_ST2+((size_t)t*NBC+blk)*4;
    p[0]=stsum[t]; p[1]=stsq[t]; p[2]=fdec(stmn[t]); p[3]=fdec(stmx[t]);
  }
}

// ---------------- KE: bn2/relu/quant -> fc1 -> relu, min/max partials ----------------
__global__ __launch_bounds__(256) void ke_kernel(InPtrs in, const float* __restrict__ wsr, float* __restrict__ wsw){
  const int t=threadIdx.x, blk=blockIdx.x;
  __shared__ float xs[6400];   // 16 img x 400
  __shared__ float red[256];
  __shared__ float sm[16], sisd[16];
  const float lvf=(float)((1<<in.qb[0])-1);
  float tmn=(t<16)?wsr[OFF_BN2+t*4+2]:3.4e38f;
  float tmx=(t<16)?wsr[OFF_BN2+t*4+3]:-3.4e38f;
  if (t<16){ sm[t]=wsr[OFF_BN2+t*4]; sisd[t]=1.0f/wsr[OFF_BN2+t*4+1]; }
  const float rmn=blk_min(tmn,red,t);
  const float rmx=blk_max(tmx,red,t);
  const float s3=(fmaxf(rmx,0.f)-fmaxf(rmn,0.f))/lvf;
  const float inv_s3=1.0f/s3;
  const float inv_s3w=1.0f/wsr[OFF_WSC+2];
  const int b0=blk*16;
  for (int i=t;i<6400;i+=256){
    int img=i/400, k=i-img*400;
    int ch=k/25;
    float y=wsr[OFF_Y2P+(size_t)(b0+img)*400+k];
    float bn=(y-sm[ch])*sisd[ch];
    float r=fmaxf(bn,0.f);
    xs[i]=fminf(rintf(r*inv_s3),lvf)*s3;
  }
  __syncthreads();
  const int iml=t>>4, og=t&15;
  const float* xr=xs+iml*400;
  const float* w3=wsr+OFF_W3;
  float acc[8];
  #pragma unroll
  for (int j=0;j<8;++j) acc[j]=0.f;
  #pragma unroll 4
  for (int k=0;k<400;++k){
    float xv=xr[k];
    const float4* wp=(const float4*)(w3+k*128+og*8);
    float4 wa=wp[0], wb=wp[1];
    acc[0]=fmaf(xv,wa.x,acc[0]); acc[1]=fmaf(xv,wa.y,acc[1]);
    acc[2]=fmaf(xv,wa.z,acc[2]); acc[3]=fmaf(xv,wa.w,acc[3]);
    acc[4]=fmaf(xv,wb.x,acc[4]); acc[5]=fmaf(xv,wb.y,acc[5]);
    acc[6]=fmaf(xv,wb.z,acc[6]); acc[7]=fmaf(xv,wb.w,acc[7]);
  }
  float hmn=3.4e38f,hmx=-3.4e38f;
  #pragma unroll
  for (int j=0;j<8;++j){
    float h=fmaxf(acc[j]*inv_s3w,0.f);
    wsw[OFF_H3+(size_t)(b0+iml)*128+og*8+j]=h;
    hmn=fminf(hmn,h); hmx=fmaxf(hmx,h);
  }
  float bmn=blk_min(hmn,red,t);
  float bmx=blk_max(hmx,red,t);
  if (t==0){ wsw[OFF_MME+blk*2]=bmn; wsw[OFF_MME+blk*2+1]=bmx; }
}

// ---------------- KF: quant -> fc2 -> log_softmax ----------------
__global__ __launch_bounds__(256) void kf_kernel(InPtrs in, const float* __restrict__ wsr, float* __restrict__ out){
  const int t=threadIdx.x, blk=blockIdx.x;
  __shared__ float red[256];
  __shared__ float w4s[1280];
  const float lvf=(float)((1<<in.qb[0])-1);
  float lmn=3.4e38f,lmx=-3.4e38f;
  for (int i=t;i<NBE;i+=256){ lmn=fminf(lmn,wsr[OFF_MME+2*i]); lmx=fmaxf(lmx,wsr[OFF_MME+2*i+1]); }
  for (int i=t;i<1280;i+=256) w4s[i]=wsr[OFF_W4+i];
  const float hmn=blk_min(lmn,red,t);
  const float hmx=blk_max(lmx,red,t);
  const float s4=(hmx-hmn)/lvf;
  const float inv_s4=1.0f/s4;
  const float inv_s4w=1.0f/wsr[OFF_WSC+3];
  const int row=blk*256+t;
  const float* hr=wsr+OFF_H3+(size_t)row*128;
  float acc[10];
  #pragma unroll
  for (int j=0;j<10;++j) acc[j]=0.f;
  for (int k=0;k<128;++k){
    float h=hr[k];
    float x3=fminf(rintf(h*inv_s4),lvf)*s4;
    #pragma unroll
    for (int j=0;j<10;++j) acc[j]=fmaf(x3,w4s[j*128+k],acc[j]);
  }
  float mx=-3.4e38f;
  #pragma unroll
  for (int j=0;j<10;++j){ acc[j]*=inv_s4w; mx=fmaxf(mx,acc[j]); }
  float se=0.f;
  #pragma unroll
  for (int j=0;j<10;++j) se+=expf(acc[j]-mx);
  const float ls=logf(se);
  #pragma unroll
  for (int j=0;j<10;++j) out[row*10+j]=acc[j]-mx-ls;
}

extern "C" void kernel_launch(void* const* d_in, const int* in_sizes, int n_in,
                              void* d_out, int out_size, void* d_ws, size_t ws_size,
                              hipStream_t stream){
  (void)in_sizes; (void)n_in; (void)out_size; (void)ws_size;
  InPtrs P;
  P.x=(const float*)d_in[0];
  for (int l=0;l<4;++l){
    P.sc[l]=(const float*)d_in[1+l*4];
    P.sg[l]=(const float*)d_in[2+l*4];
    P.on[l]=(const float*)d_in[3+l*4];
    P.ze[l]=(const float*)d_in[4+l*4];
  }
  P.qb=(const int*)d_in[17];
  float* ws=(float*)d_ws;

  hipLaunchKernelGGL(kw_kernel, dim3(4),   dim3(256), 0, stream, P, ws);
  hipLaunchKernelGGL(ka_kernel, dim3(NBA), dim3(256), 0, stream, P, ws);
  hipLaunchKernelGGL(kb_kernel, dim3(NBB), dim3(256), 0, stream, P, ws, ws);
  hipLaunchKernelGGL(kstat_kernel, dim3(64), dim3(256), 0, stream, ws, ws,
                     (unsigned long long)OFF_ST1, NBB, 4096.f*144.f, (unsigned long long)OFF_BN1);
  hipLaunchKernelGGL(kc_kernel, dim3(NBC), dim3(256), 0, stream, P, ws, ws);
  hipLaunchKernelGGL(kstat_kernel, dim3(16), dim3(256), 0, stream, ws, ws,
                     (unsigned long long)OFF_ST2, NBC, 4096.f*25.f, (unsigned long long)OFF_BN2);
  hipLaunchKernelGGL(ke_kernel, dim3(NBE), dim3(256), 0, stream, P, ws, ws);
  hipLaunchKernelGGL(kf_kernel, dim3(16),  dim3(256), 0, stream, P, ws, (float*)d_out);
}

// Round 2
// 391.775 us; speedup vs baseline: 1.5011x; 1.5011x over previous
//
#include <hip/hip_runtime.h>
#include <hip/hip_bf16.h>
#include <math.h>

#define DEV __device__ __forceinline__

constexpr int BATCH = 4096;
constexpr int NBA = 512;   // pool/minmax blocks
constexpr int NBB = 512;   // conv1-stats blocks (8 img each)
constexpr int NBC = 2048;  // fused conv blocks (2 img each)
constexpr int NBE = 256;   // fc1 blocks (16 img each)

// workspace layout (float offsets)
constexpr size_t OFF_POOLED = 0;                            // 4096*196
constexpr size_t OFF_Y2P = OFF_POOLED + (size_t)BATCH*196;  // 4096*400 (pooled conv2 out)
constexpr size_t OFF_H3  = OFF_Y2P + (size_t)BATCH*400;     // 4096*128 (fc1 post-relu)
constexpr size_t OFF_W1  = OFF_H3 + (size_t)BATCH*128;      // 576
constexpr size_t OFF_W2  = OFF_W1 + 576;                    // 9216, layout [(icg*9+ky*3+kx)*64 + sub*16 + oc]
constexpr size_t OFF_W3  = OFF_W2 + 9216;                   // 51200, layout [k*128+oc]
constexpr size_t OFF_W4  = OFF_W3 + 51200;                  // 1280, natural [oc*128+k]
constexpr size_t OFF_WSC = OFF_W4 + 1280;                   // 4 layer scales
constexpr size_t OFF_MMA = OFF_WSC + 4;                     // NBA*2 pooled min/max partials
constexpr size_t OFF_ST1 = OFF_MMA + (size_t)NBA*2;         // 64*NBB*4 conv1 channel stats partials
constexpr size_t OFF_BN1 = OFF_ST1 + (size_t)64*NBB*4;      // 64*4 {mean, sd, tmin, tmax}
constexpr size_t OFF_ST2 = OFF_BN1 + 256;                   // 16*NBC*4
constexpr size_t OFF_BN2 = OFF_ST2 + (size_t)16*NBC*4;      // 16*4
constexpr size_t OFF_MME = OFF_BN2 + 64;                    // NBE*2 fc1 min/max partials
constexpr size_t WS_FLOATS = OFF_MME + (size_t)NBE*2;       // ~3.23M floats ~ 13 MB

struct InPtrs {
  const float* x;
  const float* sc[4];
  const float* sg[4];
  const float* on[4];
  const float* ze[4];
  const int* qb;
};

DEV unsigned fenc(float f){ unsigned u=__float_as_uint(f); return (u&0x80000000u)? ~u : (u|0x80000000u); }
DEV float fdec(unsigned e){ return __uint_as_float((e&0x80000000u)? (e&0x7fffffffu) : ~e); }

DEV float blk_min(float v, float* red, int t){
  red[t]=v; __syncthreads();
  for (int s=128;s>0;s>>=1){ if(t<s) red[t]=fminf(red[t],red[t+s]); __syncthreads(); }
  float r=red[0]; __syncthreads();
  return r;
}
DEV float blk_max(float v, float* red, int t){
  red[t]=v; __syncthreads();
  for (int s=128;s>0;s>>=1){ if(t<s) red[t]=fmaxf(red[t],red[t+s]); __syncthreads(); }
  float r=red[0]; __syncthreads();
  return r;
}
DEV float blk_sum(float v, float* red, int t){
  red[t]=v; __syncthreads();
  for (int s=128;s>0;s>>=1){ if(t<s) red[t]+=red[t+s]; __syncthreads(); }
  float r=red[0]; __syncthreads();
  return r;
}

DEV void loadrow16(const float* p, float* r){
  const float4* q=(const float4*)p;
  float4 a=q[0],b=q[1],c=q[2],d=q[3];
  r[0]=a.x;r[1]=a.y;r[2]=a.z;r[3]=a.w;
  r[4]=b.x;r[5]=b.y;r[6]=b.z;r[7]=b.w;
  r[8]=c.x;r[9]=c.y;r[10]=c.z;r[11]=c.w;
  r[12]=d.x;r[13]=d.y;r[14]=d.z;r[15]=d.w;
}

// one 12-wide conv1 output row -> channel stats (v = conv/scale1w)
DEV void c1row_stat(const float* ra,const float* rb,const float* rc,const float* w,
                    float inv_s1w,float& sum,float& sq,float& vmn,float& vmx){
  #pragma unroll
  for (int x=0;x<12;++x){
    float a=ra[x]*w[0];
    a=fmaf(ra[x+1],w[1],a); a=fmaf(ra[x+2],w[2],a);
    a=fmaf(rb[x],w[3],a);   a=fmaf(rb[x+1],w[4],a); a=fmaf(rb[x+2],w[5],a);
    a=fmaf(rc[x],w[6],a);   a=fmaf(rc[x+1],w[7],a); a=fmaf(rc[x+2],w[8],a);
    float v=a*inv_s1w;
    sum+=v; sq=fmaf(v,v,sq); vmn=fminf(vmn,v); vmx=fmaxf(vmx,v);
  }
}

// one 12-wide conv1 row -> bn+relu+quant -> packed u8 code in LDS
DEV void c1row_q(const float* ra,const float* rb,const float* rc,const float* w,
                 float Ac,float Bc,float inv_s2,float lvf,int y,int c,unsigned char* a1b){
  const int icg=c>>2, sub=c&3;
  #pragma unroll
  for (int x=0;x<12;++x){
    float a=ra[x]*w[0];
    a=fmaf(ra[x+1],w[1],a); a=fmaf(ra[x+2],w[2],a);
    a=fmaf(rb[x],w[3],a);   a=fmaf(rb[x+1],w[4],a); a=fmaf(rb[x+2],w[5],a);
    a=fmaf(rc[x],w[6],a);   a=fmaf(rc[x+1],w[7],a); a=fmaf(rc[x+2],w[8],a);
    float bnv=fmaf(a,Ac,Bc);
    float r=fmaxf(bnv,0.f);
    float irf=fminf(rintf(r*inv_s2),lvf);
    a1b[((icg*144+y*12+x)<<2)+sub]=(unsigned char)irf;
  }
}

DEV void fma16(float cs, const float* wp, float* acc){
  const float4* w4=(const float4*)wp;
  float4 a=w4[0],b=w4[1],c=w4[2],d=w4[3];
  acc[0]=fmaf(cs,a.x,acc[0]);  acc[1]=fmaf(cs,a.y,acc[1]);  acc[2]=fmaf(cs,a.z,acc[2]);  acc[3]=fmaf(cs,a.w,acc[3]);
  acc[4]=fmaf(cs,b.x,acc[4]);  acc[5]=fmaf(cs,b.y,acc[5]);  acc[6]=fmaf(cs,b.z,acc[6]);  acc[7]=fmaf(cs,b.w,acc[7]);
  acc[8]=fmaf(cs,c.x,acc[8]);  acc[9]=fmaf(cs,c.y,acc[9]);  acc[10]=fmaf(cs,c.z,acc[10]); acc[11]=fmaf(cs,c.w,acc[11]);
  acc[12]=fmaf(cs,d.x,acc[12]); acc[13]=fmaf(cs,d.y,acc[13]); acc[14]=fmaf(cs,d.z,acc[14]); acc[15]=fmaf(cs,d.w,acc[15]);
}

// ---------------- KW: blended weights via exact radix-select top-k of |scores| ----------------
// 1024 thr/block, one block per layer. Latency-tolerant: float4 loads, parallel
// suffix-scan bucket search (was: rolled scalar loads + serial t==0 scan = ~300us).

// find bucket b (scanning from top) where cumulative count first reaches kk,
// and remainder r = kk - (count strictly above b). All 1024 threads participate.
DEV int2 find_hist(const int* hist, int nbins, int kk, int t, int* suf, int* sh2){
  const int G=(nbins+1023)>>10;
  const int lo=t*G, hi=(lo+G<nbins)?(lo+G):nbins;
  int g=0;
  for (int b=lo;b<hi;++b) g+=hist[b];
  suf[t]=g; __syncthreads();
  #pragma unroll
  for (int s=1;s<1024;s<<=1){
    int add=(t+s<1024)?suf[t+s]:0;
    __syncthreads();
    suf[t]+=add;
    __syncthreads();
  }
  const int S=suf[t];
  const int Snext=(t<1023)?suf[t+1]:0;
  if (S>=kk && Snext<kk){
    int c2=Snext;
    for (int b=hi-1;b>=lo;--b){
      c2+=hist[b];
      if (c2>=kk){ sh2[0]=b; sh2[1]=kk-(c2-hist[b]); break; }
    }
  }
  __syncthreads();
  int2 r=make_int2(sh2[0],sh2[1]);
  __syncthreads();
  return r;
}

__global__ __launch_bounds__(1024) void kw_kernel(InPtrs in, float* __restrict__ ws){
  const int t=threadIdx.x;
  const int L=blockIdx.x;
  const int Ns[4]={576,9216,51200,1280};
  const int fans[4]={9,576,400,128};
  const int N=Ns[L];
  const int n4=N>>2;
  const int K=N>>1;
  const float4* sc4=(const float4*)in.sc[L];
  __shared__ int hist[4096];
  __shared__ int suf[1024];
  __shared__ int sh2[2];

  // pass 1: top 12 bits of |score| bits
  for (int i=t;i<4096;i+=1024) hist[i]=0;
  __syncthreads();
  for (int i=t;i<n4;i+=1024){
    float4 v=sc4[i];
    atomicAdd(&hist[(__float_as_uint(v.x)&0x7fffffffu)>>19],1);
    atomicAdd(&hist[(__float_as_uint(v.y)&0x7fffffffu)>>19],1);
    atomicAdd(&hist[(__float_as_uint(v.z)&0x7fffffffu)>>19],1);
    atomicAdd(&hist[(__float_as_uint(v.w)&0x7fffffffu)>>19],1);
  }
  __syncthreads();
  int2 f1=find_hist(hist,4096,K,t,suf,sh2);
  const unsigned b0=(unsigned)f1.x; const int r1=f1.y;

  // pass 2: mid 12 bits within bucket b0
  for (int i=t;i<4096;i+=1024) hist[i]=0;
  __syncthreads();
  for (int i=t;i<n4;i+=1024){
    float4 v=sc4[i];
    unsigned ux=__float_as_uint(v.x)&0x7fffffffu;
    unsigned uy=__float_as_uint(v.y)&0x7fffffffu;
    unsigned uz=__float_as_uint(v.z)&0x7fffffffu;
    unsigned uw=__float_as_uint(v.w)&0x7fffffffu;
    if ((ux>>19)==b0) atomicAdd(&hist[(ux>>7)&0xfffu],1);
    if ((uy>>19)==b0) atomicAdd(&hist[(uy>>7)&0xfffu],1);
    if ((uz>>19)==b0) atomicAdd(&hist[(uz>>7)&0xfffu],1);
    if ((uw>>19)==b0) atomicAdd(&hist[(uw>>7)&0xfffu],1);
  }
  __syncthreads();
  int2 f2=find_hist(hist,4096,r1,t,suf,sh2);
  const unsigned b1=(unsigned)f2.x; const int r2=f2.y;
  const unsigned pre=(b0<<12)|b1;

  // pass 3: low 7 bits within prefix
  for (int i=t;i<128;i+=1024) ;
  if (t<128) hist[t]=0;
  __syncthreads();
  for (int i=t;i<n4;i+=1024){
    float4 v=sc4[i];
    unsigned ux=__float_as_uint(v.x)&0x7fffffffu;
    unsigned uy=__float_as_uint(v.y)&0x7fffffffu;
    unsigned uz=__float_as_uint(v.z)&0x7fffffffu;
    unsigned uw=__float_as_uint(v.w)&0x7fffffffu;
    if ((ux>>7)==pre) atomicAdd(&hist[ux&127u],1);
    if ((uy>>7)==pre) atomicAdd(&hist[uy&127u],1);
    if ((uz>>7)==pre) atomicAdd(&hist[uz&127u],1);
    if ((uw>>7)==pre) atomicAdd(&hist[uw&127u],1);
  }
  __syncthreads();
  int2 f3=find_hist(hist,128,r2,t,suf,sh2);
  const unsigned T=(pre<<7)|(unsigned)f3.x;  // bits of k-th largest |score|

  // write blended weights (layer-specific layout) + scale = mean(hw_one)*sqrt(fan)/2
  const float4* sg4=(const float4*)in.sg[L];
  const float4* on4=(const float4*)in.on[L];
  const float4* ze4=(const float4*)in.ze[L];
  float* wout=ws+(L==0?OFF_W1: L==1?OFF_W2 : L==2?OFF_W3 : OFF_W4);
  double lsum=0.0;
  for (int i4=t;i4<n4;i4+=1024){
    float4 s=sc4[i4], g=sg4[i4], o=on4[i4], z=ze4[i4];
    float sv[4]={s.x,s.y,s.z,s.w}, gv[4]={g.x,g.y,g.z,g.w};
    float ov[4]={o.x,o.y,o.z,o.w}, zv[4]={z.x,z.y,z.z,z.w};
    #pragma unroll
    for (int j=0;j<4;++j){
      int i=i4*4+j;
      unsigned u=__float_as_uint(sv[j])&0x7fffffffu;
      float w=gv[j]*((u>=T)? ov[j] : zv[j]);
      int o2;
      if (L==0) o2=i;
      else if (L==1){ int oc=i/576; int r=i-oc*576; int ic=r/9; int rr=r-ic*9;
                      o2=((ic>>2)*9+rr)*64+(ic&3)*16+oc; }
      else if (L==2){ int oc=i/400; int kk=i-oc*400; o2=kk*128+oc; }
      else o2=i;
      wout[o2]=w;
      lsum+=(double)ov[j];
    }
  }
  __shared__ double dred[1024];
  dred[t]=lsum; __syncthreads();
  for (int s=512;s>0;s>>=1){ if(t<s) dred[t]+=dred[t+s]; __syncthreads(); }
  if (t==0) ws[OFF_WSC+L]=(float)((dred[0]/(double)N)*sqrt((double)fans[L])*0.5);
}

// ---------------- KA: 2x2 maxpool + pooled min/max partials ----------------
__global__ __launch_bounds__(256) void ka_kernel(InPtrs in, float* __restrict__ ws){
  const int t=threadIdx.x, blk=blockIdx.x;
  const float* x=in.x;
  float* pooled=ws+OFF_POOLED;
  float lmn=3.4e38f, lmx=-3.4e38f;
  for (int p=blk*256+t; p<BATCH*196; p+=NBA*256){
    int b=p/196, r=p-b*196;
    int oy=r/14, ox=r-oy*14;
    const float* px=x+b*784+oy*56+ox*2;
    float m=fmaxf(fmaxf(px[0],px[1]),fmaxf(px[28],px[29]));
    pooled[p]=m;
    lmn=fminf(lmn,m); lmx=fmaxf(lmx,m);
  }
  __shared__ float red[256];
  float bmn=blk_min(lmn,red,t);
  float bmx=blk_max(lmx,red,t);
  if (t==0){ ws[OFF_MMA+blk*2]=bmn; ws[OFF_MMA+blk*2+1]=bmx; }
}

// ---------------- KB: conv1 (recomputed) -> per-channel BN1 stats partials ----------------
__global__ __launch_bounds__(256) void kb_kernel(InPtrs in, const float* __restrict__ wsr, float* __restrict__ wsw){
  const int t=threadIdx.x, blk=blockIdx.x;
  __shared__ __align__(16) float qxs[224];
  __shared__ float red[256];
  const float* pooled=wsr+OFF_POOLED;
  float lmn=3.4e38f,lmx=-3.4e38f;
  for (int i=t;i<NBA;i+=256){ lmn=fminf(lmn,wsr[OFF_MMA+2*i]); lmx=fmaxf(lmx,wsr[OFF_MMA+2*i+1]); }
  const float mn0=blk_min(lmn,red,t);
  const float mx0=blk_max(lmx,red,t);
  const float lvf=(float)((1<<in.qb[0])-1);
  const float s0=(mx0-mn0)/lvf;
  const float inv_s0=1.0f/s0;
  const float zp0=floorf(mn0/s0);
  const float inv_s1w=1.0f/wsr[OFF_WSC+0];
  const int c=t>>2, q=t&3;
  float w[9];
  #pragma unroll
  for (int j=0;j<9;++j) w[j]=wsr[OFF_W1+c*9+j];
  float sum=0.f,sq=0.f,vmn=3.4e38f,vmx=-3.4e38f;
  #pragma unroll 1
  for (int ii=0;ii<8;++ii){
    const int b=blk*8+ii;
    __syncthreads();
    for (int i=t;i<224;i+=256){
      int row=i>>4,col=i&15;
      float v=0.f;
      if (col<14){ float xx=pooled[b*196+row*14+col]; v=(rintf((xx-mn0)*inv_s0)+zp0)*s0; }
      qxs[i]=v;
    }
    __syncthreads();
    float rA[16],rB[16],rC[16];
    const int y0=q*3;
    loadrow16(qxs+y0*16,rA);
    loadrow16(qxs+(y0+1)*16,rB);
    loadrow16(qxs+(y0+2)*16,rC); c1row_stat(rA,rB,rC,w,inv_s1w,sum,sq,vmn,vmx);
    loadrow16(qxs+(y0+3)*16,rA); c1row_stat(rB,rC,rA,w,inv_s1w,sum,sq,vmn,vmx);
    loadrow16(qxs+(y0+4)*16,rB); c1row_stat(rC,rA,rB,w,inv_s1w,sum,sq,vmn,vmx);
  }
  #pragma unroll
  for (int d=1;d<4;d<<=1){
    sum+=__shfl_xor(sum,d);
    sq +=__shfl_xor(sq,d);
    vmn=fminf(vmn,__shfl_xor(vmn,d));
    vmx=fmaxf(vmx,__shfl_xor(vmx,d));
  }
  if (q==0){
    float* p=wsw+OFF_ST1+((size_t)c*NBB+blk)*4;
    p[0]=sum; p[1]=sq; p[2]=vmn; p[3]=vmx;
  }
}

// ---------------- kstat: per-channel partial reduce -> {mean, sd, tmin, tmax} ----------------
__global__ __launch_bounds__(256) void kstat_kernel(const float* __restrict__ wsr, float* __restrict__ wsw,
                                                    unsigned long long inoff, int nparts, float Nf,
                                                    unsigned long long outoff){
  const int c=blockIdx.x, t=threadIdx.x;
  __shared__ float red[256];
  const float* p=wsr+inoff+(size_t)c*nparts*4;
  float sum=0.f,sq=0.f,mn=3.4e38f,mx=-3.4e38f;
  for (int i=t;i<nparts;i+=256){
    sum+=p[i*4]; sq+=p[i*4+1];
    mn=fminf(mn,p[i*4+2]); mx=fmaxf(mx,p[i*4+3]);
  }
  float S=blk_sum(sum,red,t);
  float Q=blk_sum(sq,red,t);
  float MN=blk_min(mn,red,t);
  float MX=blk_max(mx,red,t);
  if (t==0){
    float mean=S/Nf;
    float var=fmaxf(Q/Nf-mean*mean,0.f);
    float sd=sqrtf(var+1e-5f);
    float* o=wsw+outoff+c*4;
    o[0]=mean; o[1]=sd; o[2]=(MN-mean)/sd; o[3]=(MX-mean)/sd;
  }
}

// ---------------- KC: fused conv1->bn1/relu/quant->conv2->pool + BN2 stats partials ----------------
__global__ __launch_bounds__(256) void kc_kernel(InPtrs in, const float* __restrict__ wsr, float* __restrict__ wsw){
  const int t=threadIdx.x, blk=blockIdx.x;
  __shared__ __align__(16) float qxs[448];      // 2 img x 14x16 quantized input
  __shared__ unsigned sa1[4608];                // 2 img x [icg][12x12] packed u8 codes (4 ic / u32)
  __shared__ float c2s[3200];                   // 2 img x [oc][10x10] conv2 out
  __shared__ float sA[64], sB[64];
  __shared__ float red[256];
  __shared__ float stsum[16], stsq[16];
  __shared__ unsigned stmn[16], stmx[16];
  const float* pooled=wsr+OFF_POOLED;
  float lmn=3.4e38f,lmx=-3.4e38f;
  for (int i=t;i<NBA;i+=256){ lmn=fminf(lmn,wsr[OFF_MMA+2*i]); lmx=fmaxf(lmx,wsr[OFF_MMA+2*i+1]); }
  const float mn0=blk_min(lmn,red,t);
  const float mx0=blk_max(lmx,red,t);
  const float lvf=(float)((1<<in.qb[0])-1);
  const float s0=(mx0-mn0)/lvf, inv_s0=1.0f/s0, zp0=floorf(mn0/s0);
  const float s1w=wsr[OFF_WSC+0], s2w=wsr[OFF_WSC+1];
  if (t<64){
    float m=wsr[OFF_BN1+t*4], sd=wsr[OFF_BN1+t*4+1];
    sA[t]=1.0f/(s1w*sd);
    sB[t]=-m/sd;
  }
  float tmn=(t<64)?wsr[OFF_BN1+t*4+2]:3.4e38f;
  float tmx=(t<64)?wsr[OFF_BN1+t*4+3]:-3.4e38f;
  const float rmn=blk_min(tmn,red,t);
  const float rmx=blk_max(tmx,red,t);
  const float s2=(fmaxf(rmx,0.f)-fmaxf(rmn,0.f))/lvf;
  const float inv_s2=1.0f/s2;
  const float g2=s2/s2w;
  if (t<16){ stsum[t]=0.f; stsq[t]=0.f; stmn[t]=0xFFFFFFFFu; stmx[t]=0u; }
  const int b0=blk*2;
  __syncthreads();

  // quantized pooled input, both images
  for (int i=t;i<448;i+=256){
    int img=(i>=224), r=i-img*224;
    int row=r>>4, col=r&15;
    float v=0.f;
    if (col<14){ float xx=pooled[(b0+img)*196+row*14+col]; v=(rintf((xx-mn0)*inv_s0)+zp0)*s0; }
    qxs[i]=v;
  }
  __syncthreads();

  // conv1 + bn + relu + quant -> packed codes
  {
    const int img=t>>7, lp=t&127;
    const int c=lp>>1, q=lp&1;
    const float Ac=sA[c], Bc=sB[c];
    float w[9];
    #pragma unroll
    for (int j=0;j<9;++j) w[j]=wsr[OFF_W1+c*9+j];
    const float* qx=qxs+img*224;
    unsigned char* a1b=(unsigned char*)(sa1+img*2304);
    float rA[16],rB[16],rC[16];
    const int y0=q*6;
    loadrow16(qx+y0*16,rA);
    loadrow16(qx+(y0+1)*16,rB);
    loadrow16(qx+(y0+2)*16,rC); c1row_q(rA,rB,rC,w,Ac,Bc,inv_s2,lvf,y0+0,c,a1b);
    loadrow16(qx+(y0+3)*16,rA); c1row_q(rB,rC,rA,w,Ac,Bc,inv_s2,lvf,y0+1,c,a1b);
    loadrow16(qx+(y0+4)*16,rB); c1row_q(rC,rA,rB,w,Ac,Bc,inv_s2,lvf,y0+2,c,a1b);
    loadrow16(qx+(y0+5)*16,rC); c1row_q(rA,rB,rC,w,Ac,Bc,inv_s2,lvf,y0+3,c,a1b);
    loadrow16(qx+(y0+6)*16,rA); c1row_q(rB,rC,rA,w,Ac,Bc,inv_s2,lvf,y0+4,c,a1b);
    loadrow16(qx+(y0+7)*16,rB); c1row_q(rC,rA,rB,w,Ac,Bc,inv_s2,lvf,y0+5,c,a1b);
  }
  __syncthreads();

  // conv2: lane = spatial position, acc over 16 oc; weights wave-uniform
  {
    const int img=t>>7, lp=t&127;
    const bool act=lp<100;
    const int p=act?lp:0;
    const int py=p/10, px=p-py*10;
    const unsigned* a1w=sa1+img*2304;
    const float* w2=wsr+OFF_W2;
    float acc[16];
    #pragma unroll
    for (int j=0;j<16;++j) acc[j]=0.f;
    const int off=py*12+px;
    #pragma unroll 1
    for (int icg=0;icg<16;++icg){
      const unsigned* bs=a1w+icg*144+off;
      const float* wb=w2+icg*576;
      #pragma unroll
      for (int ky=0;ky<3;++ky){
        #pragma unroll
        for (int kx=0;kx<3;++kx){
          unsigned code=bs[ky*12+kx];
          const float* wp=wb+(ky*3+kx)*64;
          fma16((float)(code&255u),       wp,    acc);
          fma16((float)((code>>8)&255u),  wp+16, acc);
          fma16((float)((code>>16)&255u), wp+32, acc);
          fma16((float)(code>>24),        wp+48, acc);
        }
      }
    }
    if (act){
      #pragma unroll
      for (int j=0;j<16;++j) c2s[img*1600+j*100+lp]=acc[j]*g2;
    }
  }
  __syncthreads();

  // 2x2 maxpool + per-channel stats
  for (int i=t;i<800;i+=256){
    int img=(i>=400), r=i-img*400;
    int ch=r/25, pp=r-ch*25;
    int py=pp/5, px=pp-py*5;
    const float* cc=c2s+img*1600+ch*100;
    int base=py*20+px*2;
    float v=fmaxf(fmaxf(cc[base],cc[base+1]),fmaxf(cc[base+10],cc[base+11]));
    wsw[OFF_Y2P+(size_t)(b0+img)*400+r]=v;
    atomicAdd(&stsum[ch],v);
    atomicAdd(&stsq[ch],v*v);
    atomicMin(&stmn[ch],fenc(v));
    atomicMax(&stmx[ch],fenc(v));
  }
  __syncthreads();
  if (t<16){
    float* p=wsw+OFF_ST2+((size_t)t*NBC+blk)*4;
    p[0]=stsum[t]; p[1]=stsq[t]; p[2]=fdec(stmn[t]); p[3]=fdec(stmx[t]);
  }
}

// ---------------- KE: bn2/relu/quant -> fc1 -> relu, min/max partials ----------------
__global__ __launch_bounds__(256) void ke_kernel(InPtrs in, const float* __restrict__ wsr, float* __restrict__ wsw){
  const int t=threadIdx.x, blk=blockIdx.x;
  __shared__ float xs[6400];   // 16 img x 400
  __shared__ float red[256];
  __shared__ float sm[16], sisd[16];
  const float lvf=(float)((1<<in.qb[0])-1);
  float tmn=(t<16)?wsr[OFF_BN2+t*4+2]:3.4e38f;
  float tmx=(t<16)?wsr[OFF_BN2+t*4+3]:-3.4e38f;
  if (t<16){ sm[t]=wsr[OFF_BN2+t*4]; sisd[t]=1.0f/wsr[OFF_BN2+t*4+1]; }
  const float rmn=blk_min(tmn,red,t);
  const float rmx=blk_max(tmx,red,t);
  const float s3=(fmaxf(rmx,0.f)-fmaxf(rmn,0.f))/lvf;
  const float inv_s3=1.0f/s3;
  const float inv_s3w=1.0f/wsr[OFF_WSC+2];
  const int b0=blk*16;
  for (int i=t;i<6400;i+=256){
    int img=i/400, k=i-img*400;
    int ch=k/25;
    float y=wsr[OFF_Y2P+(size_t)(b0+img)*400+k];
    float bn=(y-sm[ch])*sisd[ch];
    float r=fmaxf(bn,0.f);
    xs[i]=fminf(rintf(r*inv_s3),lvf)*s3;
  }
  __syncthreads();
  const int iml=t>>4, og=t&15;
  const float* xr=xs+iml*400;
  const float* w3=wsr+OFF_W3;
  float acc[8];
  #pragma unroll
  for (int j=0;j<8;++j) acc[j]=0.f;
  #pragma unroll 4
  for (int k=0;k<400;++k){
    float xv=xr[k];
    const float4* wp=(const float4*)(w3+k*128+og*8);
    float4 wa=wp[0], wb=wp[1];
    acc[0]=fmaf(xv,wa.x,acc[0]); acc[1]=fmaf(xv,wa.y,acc[1]);
    acc[2]=fmaf(xv,wa.z,acc[2]); acc[3]=fmaf(xv,wa.w,acc[3]);
    acc[4]=fmaf(xv,wb.x,acc[4]); acc[5]=fmaf(xv,wb.y,acc[5]);
    acc[6]=fmaf(xv,wb.z,acc[6]); acc[7]=fmaf(xv,wb.w,acc[7]);
  }
  float hmn=3.4e38f,hmx=-3.4e38f;
  #pragma unroll
  for (int j=0;j<8;++j){
    float h=fmaxf(acc[j]*inv_s3w,0.f);
    wsw[OFF_H3+(size_t)(b0+iml)*128+og*8+j]=h;
    hmn=fminf(hmn,h); hmx=fmaxf(hmx,h);
  }
  float bmn=blk_min(hmn,red,t);
  float bmx=blk_max(hmx,red,t);
  if (t==0){ wsw[OFF_MME+blk*2]=bmn; wsw[OFF_MME+blk*2+1]=bmx; }
}

// ---------------- KF: quant -> fc2 -> log_softmax ----------------
__global__ __launch_bounds__(256) void kf_kernel(InPtrs in, const float* __restrict__ wsr, float* __restrict__ out){
  const int t=threadIdx.x, blk=blockIdx.x;
  __shared__ float red[256];
  __shared__ float w4s[1280];
  const float lvf=(float)((1<<in.qb[0])-1);
  float lmn=3.4e38f,lmx=-3.4e38f;
  for (int i=t;i<NBE;i+=256){ lmn=fminf(lmn,wsr[OFF_MME+2*i]); lmx=fmaxf(lmx,wsr[OFF_MME+2*i+1]); }
  for (int i=t;i<1280;i+=256) w4s[i]=wsr[OFF_W4+i];
  const float hmn=blk_min(lmn,red,t);
  const float hmx=blk_max(lmx,red,t);
  const float s4=(hmx-hmn)/lvf;
  const float inv_s4=1.0f/s4;
  const float inv_s4w=1.0f/wsr[OFF_WSC+3];
  const int row=blk*256+t;
  const float* hr=wsr+OFF_H3+(size_t)row*128;
  float acc[10];
  #pragma unroll
  for (int j=0;j<10;++j) acc[j]=0.f;
  for (int k=0;k<128;++k){
    float h=hr[k];
    float x3=fminf(rintf(h*inv_s4),lvf)*s4;
    #pragma unroll
    for (int j=0;j<10;++j) acc[j]=fmaf(x3,w4s[j*128+k],acc[j]);
  }
  float mx=-3.4e38f;
  #pragma unroll
  for (int j=0;j<10;++j){ acc[j]*=inv_s4w; mx=fmaxf(mx,acc[j]); }
  float se=0.f;
  #pragma unroll
  for (int j=0;j<10;++j) se+=expf(acc[j]-mx);
  const float ls=logf(se);
  #pragma unroll
  for (int j=0;j<10;++j) out[row*10+j]=acc[j]-mx-ls;
}

extern "C" void kernel_launch(void* const* d_in, const int* in_sizes, int n_in,
                              void* d_out, int out_size, void* d_ws, size_t ws_size,
                              hipStream_t stream){
  (void)in_sizes; (void)n_in; (void)out_size; (void)ws_size;
  InPtrs P;
  P.x=(const float*)d_in[0];
  for (int l=0;l<4;++l){
    P.sc[l]=(const float*)d_in[1+l*4];
    P.sg[l]=(const float*)d_in[2+l*4];
    P.on[l]=(const float*)d_in[3+l*4];
    P.ze[l]=(const float*)d_in[4+l*4];
  }
  P.qb=(const int*)d_in[17];
  float* ws=(float*)d_ws;

  hipLaunchKernelGGL(kw_kernel, dim3(4),   dim3(1024), 0, stream, P, ws);
  hipLaunchKernelGGL(ka_kernel, dim3(NBA), dim3(256), 0, stream, P, ws);
  hipLaunchKernelGGL(kb_kernel, dim3(NBB), dim3(256), 0, stream, P, ws, ws);
  hipLaunchKernelGGL(kstat_kernel, dim3(64), dim3(256), 0, stream, ws, ws,
                     (unsigned long long)OFF_ST1, NBB, 4096.f*144.f, (unsigned long long)OFF_BN1);
  hipLaunchKernelGGL(kc_kernel, dim3(NBC), dim3(256), 0, stream, P, ws, ws);
  hipLaunchKernelGGL(kstat_kernel, dim3(16), dim3(256), 0, stream, ws, ws,
                     (unsigned long long)OFF_ST2, NBC, 4096.f*25.f, (unsigned long long)OFF_BN2);
  hipLaunchKernelGGL(ke_kernel, dim3(NBE), dim3(256), 0, stream, P, ws, ws);
  hipLaunchKernelGGL(kf_kernel, dim3(16),  dim3(256), 0, stream, P, ws, (float*)d_out);
}

// Round 3
// 362.325 us; speedup vs baseline: 1.6231x; 1.0813x over previous
//
#include <hip/hip_runtime.h>
#include <hip/hip_bf16.h>
#include <math.h>

#define DEV __device__ __forceinline__

constexpr int BATCH = 4096;
constexpr int NBA = 512;   // pool/minmax blocks
constexpr int NBB = 512;   // conv1-stats blocks (8 img each)
constexpr int NBC = 2048;  // fused conv blocks (2 img each)
constexpr int NBE = 256;   // fc1 blocks (16 img each)

// workspace layout (float offsets)
constexpr size_t OFF_POOLED = 0;                            // 4096*196
constexpr size_t OFF_Y2P = OFF_POOLED + (size_t)BATCH*196;  // 4096*400 (pooled conv2 out)
constexpr size_t OFF_H3  = OFF_Y2P + (size_t)BATCH*400;     // 4096*128 (fc1 post-relu)
constexpr size_t OFF_W1  = OFF_H3 + (size_t)BATCH*128;      // 576
constexpr size_t OFF_W2  = OFF_W1 + 576;                    // 9216 floats of space: holds W2 as bf16 hi[9216]+lo[9216] ushorts, [oc][kykx*64+ic]
constexpr size_t OFF_W3  = OFF_W2 + 9216;                   // 51200, layout [k*128+oc]
constexpr size_t OFF_W4  = OFF_W3 + 51200;                  // 1280, natural [oc*128+k]
constexpr size_t OFF_WSC = OFF_W4 + 1280;                   // 4 layer scales
constexpr size_t OFF_MMA = OFF_WSC + 4;                     // NBA*2 pooled min/max partials
constexpr size_t OFF_ST1 = OFF_MMA + (size_t)NBA*2;         // 64*NBB*4 conv1 channel stats partials
constexpr size_t OFF_BN1 = OFF_ST1 + (size_t)64*NBB*4;      // 64*4 {mean, sd, tmin, tmax}
constexpr size_t OFF_ST2 = OFF_BN1 + 256;                   // 16*NBC*4
constexpr size_t OFF_BN2 = OFF_ST2 + (size_t)16*NBC*4;      // 16*4
constexpr size_t OFF_MME = OFF_BN2 + 64;                    // NBE*2 fc1 min/max partials
constexpr size_t WS_FLOATS = OFF_MME + (size_t)NBE*2;       // ~3.23M floats ~ 13 MB

typedef __attribute__((ext_vector_type(8))) short bf16x8;
typedef __attribute__((ext_vector_type(4))) float f32x4;

struct InPtrs {
  const float* x;
  const float* sc[4];
  const float* sg[4];
  const float* on[4];
  const float* ze[4];
  const int* qb;
};

DEV unsigned fenc(float f){ unsigned u=__float_as_uint(f); return (u&0x80000000u)? ~u : (u|0x80000000u); }
DEV float fdec(unsigned e){ return __uint_as_float((e&0x80000000u)? (e&0x7fffffffu) : ~e); }
// fp32 -> bf16 bits, round-to-nearest-even
DEV unsigned short f2bf(float f){ unsigned u=__float_as_uint(f); return (unsigned short)((u + 0x7fffu + ((u>>16)&1u))>>16); }

DEV float blk_min(float v, float* red, int t){
  red[t]=v; __syncthreads();
  for (int s=128;s>0;s>>=1){ if(t<s) red[t]=fminf(red[t],red[t+s]); __syncthreads(); }
  float r=red[0]; __syncthreads();
  return r;
}
DEV float blk_max(float v, float* red, int t){
  red[t]=v; __syncthreads();
  for (int s=128;s>0;s>>=1){ if(t<s) red[t]=fmaxf(red[t],red[t+s]); __syncthreads(); }
  float r=red[0]; __syncthreads();
  return r;
}
DEV float blk_sum(float v, float* red, int t){
  red[t]=v; __syncthreads();
  for (int s=128;s>0;s>>=1){ if(t<s) red[t]+=red[t+s]; __syncthreads(); }
  float r=red[0]; __syncthreads();
  return r;
}

DEV void loadrow16(const float* p, float* r){
  const float4* q=(const float4*)p;
  float4 a=q[0],b=q[1],c=q[2],d=q[3];
  r[0]=a.x;r[1]=a.y;r[2]=a.z;r[3]=a.w;
  r[4]=b.x;r[5]=b.y;r[6]=b.z;r[7]=b.w;
  r[8]=c.x;r[9]=c.y;r[10]=c.z;r[11]=c.w;
  r[12]=d.x;r[13]=d.y;r[14]=d.z;r[15]=d.w;
}

DEV float conv9(const float* ra,const float* rb,const float* rc,const float* w,int x){
  float a=ra[x]*w[0];
  a=fmaf(ra[x+1],w[1],a); a=fmaf(ra[x+2],w[2],a);
  a=fmaf(rb[x],w[3],a);   a=fmaf(rb[x+1],w[4],a); a=fmaf(rb[x+2],w[5],a);
  a=fmaf(rc[x],w[6],a);   a=fmaf(rc[x+1],w[7],a); a=fmaf(rc[x+2],w[8],a);
  return a;
}

// one 12-wide conv1 output row -> channel stats (v = conv/scale1w)
DEV void c1row_stat(const float* ra,const float* rb,const float* rc,const float* w,
                    float inv_s1w,float& sum,float& sq,float& vmn,float& vmx){
  #pragma unroll
  for (int x=0;x<12;++x){
    float v=conv9(ra,rb,rc,w,x)*inv_s1w;
    sum+=v; sq=fmaf(v,v,sq); vmn=fminf(vmn,v); vmx=fmaxf(vmx,v);
  }
}

// one 12-wide conv1 row, TWO channels -> bn+relu+quant -> packed 2xbf16 code dword in LDS
// adst: dword array [cell][36]; codes are integers 0..255 => exact in bf16 (low fp32 bits zero)
DEV void c1row2(const float* ra,const float* rb,const float* rc,
                const float* w0,const float* w1,
                float A0,float B0,float A1,float B1,
                float inv_s2,float lvf,int y,int p2,unsigned* adst){
  #pragma unroll
  for (int x=0;x<12;++x){
    float a0=conv9(ra,rb,rc,w0,x);
    float a1=conv9(ra,rb,rc,w1,x);
    float f0=fminf(rintf(fmaxf(fmaf(a0,A0,B0),0.f)*inv_s2),lvf);
    float f1=fminf(rintf(fmaxf(fmaf(a1,A1,B1),0.f)*inv_s2),lvf);
    unsigned pk=(__float_as_uint(f0)>>16)|(__float_as_uint(f1)&0xffff0000u);
    adst[(y*12+x)*36+p2]=pk;
  }
}

// ---------------- KW: blended weights via exact radix-select top-k of |scores| ----------------
// 1024 thr/block, one block per layer.
DEV int2 find_hist(const int* hist, int nbins, int kk, int t, int* suf, int* sh2){
  const int G=(nbins+1023)>>10;
  const int lo=t*G, hi=(lo+G<nbins)?(lo+G):nbins;
  int g=0;
  for (int b=lo;b<hi;++b) g+=hist[b];
  suf[t]=g; __syncthreads();
  #pragma unroll
  for (int s=1;s<1024;s<<=1){
    int add=(t+s<1024)?suf[t+s]:0;
    __syncthreads();
    suf[t]+=add;
    __syncthreads();
  }
  const int S=suf[t];
  const int Snext=(t<1023)?suf[t+1]:0;
  if (S>=kk && Snext<kk){
    int c2=Snext;
    for (int b=hi-1;b>=lo;--b){
      c2+=hist[b];
      if (c2>=kk){ sh2[0]=b; sh2[1]=kk-(c2-hist[b]); break; }
    }
  }
  __syncthreads();
  int2 r=make_int2(sh2[0],sh2[1]);
  __syncthreads();
  return r;
}

__global__ __launch_bounds__(1024) void kw_kernel(InPtrs in, float* __restrict__ ws){
  const int t=threadIdx.x;
  const int L=blockIdx.x;
  const int Ns[4]={576,9216,51200,1280};
  const int fans[4]={9,576,400,128};
  const int N=Ns[L];
  const int n4=N>>2;
  const int K=N>>1;
  const float4* sc4=(const float4*)in.sc[L];
  __shared__ int hist[4096];
  __shared__ int suf[1024];
  __shared__ int sh2[2];

  // pass 1: top 12 bits of |score| bits
  for (int i=t;i<4096;i+=1024) hist[i]=0;
  __syncthreads();
  for (int i=t;i<n4;i+=1024){
    float4 v=sc4[i];
    atomicAdd(&hist[(__float_as_uint(v.x)&0x7fffffffu)>>19],1);
    atomicAdd(&hist[(__float_as_uint(v.y)&0x7fffffffu)>>19],1);
    atomicAdd(&hist[(__float_as_uint(v.z)&0x7fffffffu)>>19],1);
    atomicAdd(&hist[(__float_as_uint(v.w)&0x7fffffffu)>>19],1);
  }
  __syncthreads();
  int2 f1=find_hist(hist,4096,K,t,suf,sh2);
  const unsigned b0=(unsigned)f1.x; const int r1=f1.y;

  // pass 2: mid 12 bits within bucket b0
  for (int i=t;i<4096;i+=1024) hist[i]=0;
  __syncthreads();
  for (int i=t;i<n4;i+=1024){
    float4 v=sc4[i];
    unsigned ux=__float_as_uint(v.x)&0x7fffffffu;
    unsigned uy=__float_as_uint(v.y)&0x7fffffffu;
    unsigned uz=__float_as_uint(v.z)&0x7fffffffu;
    unsigned uw=__float_as_uint(v.w)&0x7fffffffu;
    if ((ux>>19)==b0) atomicAdd(&hist[(ux>>7)&0xfffu],1);
    if ((uy>>19)==b0) atomicAdd(&hist[(uy>>7)&0xfffu],1);
    if ((uz>>19)==b0) atomicAdd(&hist[(uz>>7)&0xfffu],1);
    if ((uw>>19)==b0) atomicAdd(&hist[(uw>>7)&0xfffu],1);
  }
  __syncthreads();
  int2 f2=find_hist(hist,4096,r1,t,suf,sh2);
  const unsigned b1=(unsigned)f2.x; const int r2=f2.y;
  const unsigned pre=(b0<<12)|b1;

  // pass 3: low 7 bits within prefix
  if (t<128) hist[t]=0;
  __syncthreads();
  for (int i=t;i<n4;i+=1024){
    float4 v=sc4[i];
    unsigned ux=__float_as_uint(v.x)&0x7fffffffu;
    unsigned uy=__float_as_uint(v.y)&0x7fffffffu;
    unsigned uz=__float_as_uint(v.z)&0x7fffffffu;
    unsigned uw=__float_as_uint(v.w)&0x7fffffffu;
    if ((ux>>7)==pre) atomicAdd(&hist[ux&127u],1);
    if ((uy>>7)==pre) atomicAdd(&hist[uy&127u],1);
    if ((uz>>7)==pre) atomicAdd(&hist[uz&127u],1);
    if ((uw>>7)==pre) atomicAdd(&hist[uw&127u],1);
  }
  __syncthreads();
  int2 f3=find_hist(hist,128,r2,t,suf,sh2);
  const unsigned T=(pre<<7)|(unsigned)f3.x;  // bits of k-th largest |score|

  // write blended weights (layer-specific layout) + scale = mean(hw_one)*sqrt(fan)/2
  const float4* sg4=(const float4*)in.sg[L];
  const float4* on4=(const float4*)in.on[L];
  const float4* ze4=(const float4*)in.ze[L];
  float* wout=ws+(L==0?OFF_W1: L==2?OFF_W3 : OFF_W4);
  unsigned short* W2H=(unsigned short*)(ws+OFF_W2);
  unsigned short* W2L=W2H+9216;
  double lsum=0.0;
  for (int i4=t;i4<n4;i4+=1024){
    float4 s=sc4[i4], g=sg4[i4], o=on4[i4], z=ze4[i4];
    float sv[4]={s.x,s.y,s.z,s.w}, gv[4]={g.x,g.y,g.z,g.w};
    float ov[4]={o.x,o.y,o.z,o.w}, zv[4]={z.x,z.y,z.z,z.w};
    #pragma unroll
    for (int j=0;j<4;++j){
      int i=i4*4+j;
      unsigned u=__float_as_uint(sv[j])&0x7fffffffu;
      float w=gv[j]*((u>=T)? ov[j] : zv[j]);
      if (L==1){
        // scores2 (16,64,3,3): oc,ic,kpos -> hi/lo bf16 at [oc][kpos*64+ic]
        int oc=i/576; int r=i-oc*576; int ic=r/9; int kp=r-ic*9;
        int o2=oc*576 + kp*64 + ic;
        unsigned short hb=f2bf(w);
        float lo=w-__uint_as_float((unsigned)hb<<16);
        W2H[o2]=hb; W2L[o2]=f2bf(lo);
      } else {
        int o2;
        if (L==0) o2=i;
        else if (L==2){ int oc=i/400; int kk=i-oc*400; o2=kk*128+oc; }
        else o2=i;
        wout[o2]=w;
      }
      lsum+=(double)ov[j];
    }
  }
  __shared__ double dred[1024];
  dred[t]=lsum; __syncthreads();
  for (int s=512;s>0;s>>=1){ if(t<s) dred[t]+=dred[t+s]; __syncthreads(); }
  if (t==0) ws[OFF_WSC+L]=(float)((dred[0]/(double)N)*sqrt((double)fans[L])*0.5);
}

// ---------------- KA: 2x2 maxpool + pooled min/max partials ----------------
__global__ __launch_bounds__(256) void ka_kernel(InPtrs in, float* __restrict__ ws){
  const int t=threadIdx.x, blk=blockIdx.x;
  const float* x=in.x;
  float* pooled=ws+OFF_POOLED;
  float lmn=3.4e38f, lmx=-3.4e38f;
  for (int p=blk*256+t; p<BATCH*196; p+=NBA*256){
    int b=p/196, r=p-b*196;
    int oy=r/14, ox=r-oy*14;
    const float* px=x+b*784+oy*56+ox*2;
    float m=fmaxf(fmaxf(px[0],px[1]),fmaxf(px[28],px[29]));
    pooled[p]=m;
    lmn=fminf(lmn,m); lmx=fmaxf(lmx,m);
  }
  __shared__ float red[256];
  float bmn=blk_min(lmn,red,t);
  float bmx=blk_max(lmx,red,t);
  if (t==0){ ws[OFF_MMA+blk*2]=bmn; ws[OFF_MMA+blk*2+1]=bmx; }
}

// ---------------- KB: conv1 (recomputed) -> per-channel BN1 stats partials ----------------
__global__ __launch_bounds__(256) void kb_kernel(InPtrs in, const float* __restrict__ wsr, float* __restrict__ wsw){
  const int t=threadIdx.x, blk=blockIdx.x;
  __shared__ __align__(16) float qxs[224];
  __shared__ float red[256];
  const float* pooled=wsr+OFF_POOLED;
  float lmn=3.4e38f,lmx=-3.4e38f;
  for (int i=t;i<NBA;i+=256){ lmn=fminf(lmn,wsr[OFF_MMA+2*i]); lmx=fmaxf(lmx,wsr[OFF_MMA+2*i+1]); }
  const float mn0=blk_min(lmn,red,t);
  const float mx0=blk_max(lmx,red,t);
  const float lvf=(float)((1<<in.qb[0])-1);
  const float s0=(mx0-mn0)/lvf;
  const float inv_s0=1.0f/s0;
  const float zp0=floorf(mn0/s0);
  const float inv_s1w=1.0f/wsr[OFF_WSC+0];
  const int c=t>>2, q=t&3;
  float w[9];
  #pragma unroll
  for (int j=0;j<9;++j) w[j]=wsr[OFF_W1+c*9+j];
  float sum=0.f,sq=0.f,vmn=3.4e38f,vmx=-3.4e38f;
  #pragma unroll 1
  for (int ii=0;ii<8;++ii){
    const int b=blk*8+ii;
    __syncthreads();
    for (int i=t;i<224;i+=256){
      int row=i>>4,col=i&15;
      float v=0.f;
      if (col<14){ float xx=pooled[b*196+row*14+col]; v=(rintf((xx-mn0)*inv_s0)+zp0)*s0; }
      qxs[i]=v;
    }
    __syncthreads();
    float rA[16],rB[16],rC[16];
    const int y0=q*3;
    loadrow16(qxs+y0*16,rA);
    loadrow16(qxs+(y0+1)*16,rB);
    loadrow16(qxs+(y0+2)*16,rC); c1row_stat(rA,rB,rC,w,inv_s1w,sum,sq,vmn,vmx);
    loadrow16(qxs+(y0+3)*16,rA); c1row_stat(rB,rC,rA,w,inv_s1w,sum,sq,vmn,vmx);
    loadrow16(qxs+(y0+4)*16,rB); c1row_stat(rC,rA,rB,w,inv_s1w,sum,sq,vmn,vmx);
  }
  #pragma unroll
  for (int d=1;d<4;d<<=1){
    sum+=__shfl_xor(sum,d);
    sq +=__shfl_xor(sq,d);
    vmn=fminf(vmn,__shfl_xor(vmn,d));
    vmx=fmaxf(vmx,__shfl_xor(vmx,d));
  }
  if (q==0){
    float* p=wsw+OFF_ST1+((size_t)c*NBB+blk)*4;
    p[0]=sum; p[1]=sq; p[2]=vmn; p[3]=vmx;
  }
}

// ---------------- kstat: per-channel partial reduce -> {mean, sd, tmin, tmax} ----------------
__global__ __launch_bounds__(256) void kstat_kernel(const float* __restrict__ wsr, float* __restrict__ wsw,
                                                    unsigned long long inoff, int nparts, float Nf,
                                                    unsigned long long outoff){
  const int c=blockIdx.x, t=threadIdx.x;
  __shared__ float red[256];
  const float* p=wsr+inoff+(size_t)c*nparts*4;
  float sum=0.f,sq=0.f,mn=3.4e38f,mx=-3.4e38f;
  for (int i=t;i<nparts;i+=256){
    sum+=p[i*4]; sq+=p[i*4+1];
    mn=fminf(mn,p[i*4+2]); mx=fmaxf(mx,p[i*4+3]);
  }
  float S=blk_sum(sum,red,t);
  float Q=blk_sum(sq,red,t);
  float MN=blk_min(mn,red,t);
  float MX=blk_max(mx,red,t);
  if (t==0){
    float mean=S/Nf;
    float var=fmaxf(Q/Nf-mean*mean,0.f);
    float sd=sqrtf(var+1e-5f);
    float* o=wsw+outoff+c*4;
    o[0]=mean; o[1]=sd; o[2]=(MN-mean)/sd; o[3]=(MX-mean)/sd;
  }
}

// ---------------- KC: fused conv1->bn1/relu/quant->conv2(MFMA)->pool + BN2 stats partials ----------------
// conv2 = 9 shifted K=64 GEMMs via mfma_f32_16x16x32_bf16, weights split hi+lo bf16 (fp32-accurate).
// Activations (integer codes 0..255) are exact in bf16.
__global__ __launch_bounds__(256) void kc_kernel(InPtrs in, const float* __restrict__ wsr, float* __restrict__ wsw){
  const int t=threadIdx.x, blk=blockIdx.x;
  __shared__ __align__(16) float qxs[448];            // 2 img x 14x16 quantized input
  __shared__ __align__(16) unsigned actAd[2*144*36];  // 2 img x [cell=y*12+x][36 dwords = 64 bf16 + 8 pad] (41.5 KB)
  __shared__ __align__(16) float c2s[3200];           // 2 img x [oc][10x10] conv2 out
  __shared__ float sA[64], sB[64];
  __shared__ float red[256];
  __shared__ float stsum[16], stsq[16];
  __shared__ unsigned stmn[16], stmx[16];
  const float* pooled=wsr+OFF_POOLED;
  float lmn=3.4e38f,lmx=-3.4e38f;
  for (int i=t;i<NBA;i+=256){ lmn=fminf(lmn,wsr[OFF_MMA+2*i]); lmx=fmaxf(lmx,wsr[OFF_MMA+2*i+1]); }
  const float mn0=blk_min(lmn,red,t);
  const float mx0=blk_max(lmx,red,t);
  const float lvf=(float)((1<<in.qb[0])-1);
  const float s0=(mx0-mn0)/lvf, inv_s0=1.0f/s0, zp0=floorf(mn0/s0);
  const float s1w=wsr[OFF_WSC+0], s2w=wsr[OFF_WSC+1];
  if (t<64){
    float m=wsr[OFF_BN1+t*4], sd=wsr[OFF_BN1+t*4+1];
    sA[t]=1.0f/(s1w*sd);
    sB[t]=-m/sd;
  }
  float tmn=(t<64)?wsr[OFF_BN1+t*4+2]:3.4e38f;
  float tmx=(t<64)?wsr[OFF_BN1+t*4+3]:-3.4e38f;
  const float rmn=blk_min(tmn,red,t);
  const float rmx=blk_max(tmx,red,t);
  const float s2=(fmaxf(rmx,0.f)-fmaxf(rmn,0.f))/lvf;
  const float inv_s2=1.0f/s2;
  const float g2=s2/s2w;
  if (t<16){ stsum[t]=0.f; stsq[t]=0.f; stmn[t]=0xFFFFFFFFu; stmx[t]=0u; }
  const int b0=blk*2;
  __syncthreads();

  // quantized pooled input, both images
  for (int i=t;i<448;i+=256){
    int img=(i>=224), r=i-img*224;
    int row=r>>4, col=r&15;
    float v=0.f;
    if (col<14){ float xx=pooled[(b0+img)*196+row*14+col]; v=(rintf((xx-mn0)*inv_s0)+zp0)*s0; }
    qxs[i]=v;
  }
  __syncthreads();

  // conv1 + bn + relu + quant -> packed bf16 codes in [cell][ic] layout.
  // 128 thr/img: pair p2=0..31 (channels 2p2,2p2+1), part=0..3 (3 output rows each)
  {
    const int img=t>>7, r127=t&127;
    const int p2=r127&31, part=r127>>5;
    const int c0=p2*2, c1c=c0+1;
    const float A0=sA[c0],B0=sB[c0],A1=sA[c1c],B1=sB[c1c];
    float w0[9],w1[9];
    #pragma unroll
    for (int j=0;j<9;++j){ w0[j]=wsr[OFF_W1+c0*9+j]; w1[j]=wsr[OFF_W1+c1c*9+j]; }
    const float* qx=qxs+img*224;
    unsigned* adst=actAd+img*5184;
    float rA[16],rB[16],rC[16];
    const int y0=part*3;
    loadrow16(qx+y0*16,rA);
    loadrow16(qx+(y0+1)*16,rB);
    loadrow16(qx+(y0+2)*16,rC); c1row2(rA,rB,rC,w0,w1,A0,B0,A1,B1,inv_s2,lvf,y0+0,p2,adst);
    loadrow16(qx+(y0+3)*16,rA); c1row2(rB,rC,rA,w0,w1,A0,B0,A1,B1,inv_s2,lvf,y0+1,p2,adst);
    loadrow16(qx+(y0+4)*16,rB); c1row2(rC,rA,rB,w0,w1,A0,B0,A1,B1,inv_s2,lvf,y0+2,p2,adst);
  }
  __syncthreads();

  // conv2 via MFMA: tiles tau=0..13 (img=tau>=7, 16 positions each); wave w gets tau=w,w+4,w+8,w+12
  {
    const int w=t>>6, lane=t&63;
    const int oc=lane&15, quad=lane>>4;
    const short* actS=(const short*)actAd;
    const unsigned short* W2H=(const unsigned short*)(wsr+OFF_W2);
    const unsigned short* W2L=W2H+9216;
    const int boff=oc*576+quad*8;

    int nT=0; int abase[4]; int tinfo[4];
    for (int tau=w;tau<14;tau+=4){
      int img=(tau>=7), mt=tau-img*7;
      int posb=mt*16+(lane&15);
      int pc=posb>99?99:posb;
      int py=pc/10, px=pc-py*10;
      abase[nT]=img*10368+(py*12+px)*72+quad*8;
      tinfo[nT]=tau;
      nT++;
    }
    f32x4 acc[4];
    #pragma unroll
    for (int i=0;i<4;++i) acc[i]=(f32x4){0.f,0.f,0.f,0.f};

    #pragma unroll 1
    for (int kykx=0;kykx<9;++kykx){
      const int kb=kykx*64;
      const int co=((kykx/3)*12+(kykx%3))*72;
      #pragma unroll
      for (int s=0;s<2;++s){
        bf16x8 bh=*(const bf16x8*)(W2H+boff+kb+s*32);
        bf16x8 bl=*(const bf16x8*)(W2L+boff+kb+s*32);
        for (int i=0;i<nT;++i){
          bf16x8 a=*(const bf16x8*)(actS+abase[i]+co+s*32);
          acc[i]=__builtin_amdgcn_mfma_f32_16x16x32_bf16(a,bh,acc[i],0,0,0);
          acc[i]=__builtin_amdgcn_mfma_f32_16x16x32_bf16(a,bl,acc[i],0,0,0);
        }
      }
    }
    // C layout: col(oc)=lane&15, row(pos-in-tile)=quad*4+reg
    for (int i=0;i<nT;++i){
      int tau=tinfo[i];
      int img=(tau>=7), mt=tau-img*7;
      int pos4=mt*16+quad*4;
      if (pos4<100){
        float4* dst=(float4*)&c2s[img*1600+oc*100+pos4];
        *dst=make_float4(acc[i].x*g2,acc[i].y*g2,acc[i].z*g2,acc[i].w*g2);
      }
    }
  }
  __syncthreads();

  // 2x2 maxpool + per-channel stats
  for (int i=t;i<800;i+=256){
    int img=(i>=400), r=i-img*400;
    int ch=r/25, pp=r-ch*25;
    int py=pp/5, px=pp-py*5;
    const float* cc=c2s+img*1600+ch*100;
    int base=py*20+px*2;
    float v=fmaxf(fmaxf(cc[base],cc[base+1]),fmaxf(cc[base+10],cc[base+11]));
    wsw[OFF_Y2P+(size_t)(b0+img)*400+r]=v;
    atomicAdd(&stsum[ch],v);
    atomicAdd(&stsq[ch],v*v);
    atomicMin(&stmn[ch],fenc(v));
    atomicMax(&stmx[ch],fenc(v));
  }
  __syncthreads();
  if (t<16){
    float* p=wsw+OFF_ST2+((size_t)t*NBC+blk)*4;
    p[0]=stsum[t]; p[1]=stsq[t]; p[2]=fdec(stmn[t]); p[3]=fdec(stmx[t]);
  }
}

// ---------------- KE: bn2/relu/quant -> fc1 -> relu, min/max partials ----------------
__global__ __launch_bounds__(256) void ke_kernel(InPtrs in, const float* __restrict__ wsr, float* __restrict__ wsw){
  const int t=threadIdx.x, blk=blockIdx.x;
  __shared__ float xs[6400];   // 16 img x 400
  __shared__ float red[256];
  __shared__ float sm[16], sisd[16];
  const float lvf=(float)((1<<in.qb[0])-1);
  float tmn=(t<16)?wsr[OFF_BN2+t*4+2]:3.4e38f;
  float tmx=(t<16)?wsr[OFF_BN2+t*4+3]:-3.4e38f;
  if (t<16){ sm[t]=wsr[OFF_BN2+t*4]; sisd[t]=1.0f/wsr[OFF_BN2+t*4+1]; }
  const float rmn=blk_min(tmn,red,t);
  const float rmx=blk_max(tmx,red,t);
  const float s3=(fmaxf(rmx,0.f)-fmaxf(rmn,0.f))/lvf;
  const float inv_s3=1.0f/s3;
  const float inv_s3w=1.0f/wsr[OFF_WSC+2];
  const int b0=blk*16;
  for (int i=t;i<6400;i+=256){
    int img=i/400, k=i-img*400;
    int ch=k/25;
    float y=wsr[OFF_Y2P+(size_t)(b0+img)*400+k];
    float bn=(y-sm[ch])*sisd[ch];
    float r=fmaxf(bn,0.f);
    xs[i]=fminf(rintf(r*inv_s3),lvf)*s3;
  }
  __syncthreads();
  const int iml=t>>4, og=t&15;
  const float* xr=xs+iml*400;
  const float* w3=wsr+OFF_W3;
  float acc[8];
  #pragma unroll
  for (int j=0;j<8;++j) acc[j]=0.f;
  #pragma unroll 4
  for (int k=0;k<400;++k){
    float xv=xr[k];
    const float4* wp=(const float4*)(w3+k*128+og*8);
    float4 wa=wp[0], wb=wp[1];
    acc[0]=fmaf(xv,wa.x,acc[0]); acc[1]=fmaf(xv,wa.y,acc[1]);
    acc[2]=fmaf(xv,wa.z,acc[2]); acc[3]=fmaf(xv,wa.w,acc[3]);
    acc[4]=fmaf(xv,wb.x,acc[4]); acc[5]=fmaf(xv,wb.y,acc[5]);
    acc[6]=fmaf(xv,wb.z,acc[6]); acc[7]=fmaf(xv,wb.w,acc[7]);
  }
  float hmn=3.4e38f,hmx=-3.4e38f;
  #pragma unroll
  for (int j=0;j<8;++j){
    float h=fmaxf(acc[j]*inv_s3w,0.f);
    wsw[OFF_H3+(size_t)(b0+iml)*128+og*8+j]=h;
    hmn=fminf(hmn,h); hmx=fmaxf(hmx,h);
  }
  float bmn=blk_min(hmn,red,t);
  float bmx=blk_max(hmx,red,t);
  if (t==0){ wsw[OFF_MME+blk*2]=bmn; wsw[OFF_MME+blk*2+1]=bmx; }
}

// ---------------- KF: quant -> fc2 -> log_softmax ----------------
__global__ __launch_bounds__(256) void kf_kernel(InPtrs in, const float* __restrict__ wsr, float* __restrict__ out){
  const int t=threadIdx.x, blk=blockIdx.x;
  __shared__ float red[256];
  __shared__ float w4s[1280];
  const float lvf=(float)((1<<in.qb[0])-1);
  float lmn=3.4e38f,lmx=-3.4e38f;
  for (int i=t;i<NBE;i+=256){ lmn=fminf(lmn,wsr[OFF_MME+2*i]); lmx=fmaxf(lmx,wsr[OFF_MME+2*i+1]); }
  for (int i=t;i<1280;i+=256) w4s[i]=wsr[OFF_W4+i];
  const float hmn=blk_min(lmn,red,t);
  const float hmx=blk_max(lmx,red,t);
  const float s4=(hmx-hmn)/lvf;
  const float inv_s4=1.0f/s4;
  const float inv_s4w=1.0f/wsr[OFF_WSC+3];
  const int row=blk*256+t;
  const float* hr=wsr+OFF_H3+(size_t)row*128;
  float acc[10];
  #pragma unroll
  for (int j=0;j<10;++j) acc[j]=0.f;
  for (int k=0;k<128;++k){
    float h=hr[k];
    float x3=fminf(rintf(h*inv_s4),lvf)*s4;
    #pragma unroll
    for (int j=0;j<10;++j) acc[j]=fmaf(x3,w4s[j*128+k],acc[j]);
  }
  float mx=-3.4e38f;
  #pragma unroll
  for (int j=0;j<10;++j){ acc[j]*=inv_s4w; mx=fmaxf(mx,acc[j]); }
  float se=0.f;
  #pragma unroll
  for (int j=0;j<10;++j) se+=expf(acc[j]-mx);
  const float ls=logf(se);
  #pragma unroll
  for (int j=0;j<10;++j) out[row*10+j]=acc[j]-mx-ls;
}

extern "C" void kernel_launch(void* const* d_in, const int* in_sizes, int n_in,
                              void* d_out, int out_size, void* d_ws, size_t ws_size,
                              hipStream_t stream){
  (void)in_sizes; (void)n_in; (void)out_size; (void)ws_size;
  InPtrs P;
  P.x=(const float*)d_in[0];
  for (int l=0;l<4;++l){
    P.sc[l]=(const float*)d_in[1+l*4];
    P.sg[l]=(const float*)d_in[2+l*4];
    P.on[l]=(const float*)d_in[3+l*4];
    P.ze[l]=(const float*)d_in[4+l*4];
  }
  P.qb=(const int*)d_in[17];
  float* ws=(float*)d_ws;

  hipLaunchKernelGGL(kw_kernel, dim3(4),   dim3(1024), 0, stream, P, ws);
  hipLaunchKernelGGL(ka_kernel, dim3(NBA), dim3(256), 0, stream, P, ws);
  hipLaunchKernelGGL(kb_kernel, dim3(NBB), dim3(256), 0, stream, P, ws, ws);
  hipLaunchKernelGGL(kstat_kernel, dim3(64), dim3(256), 0, stream, ws, ws,
                     (unsigned long long)OFF_ST1, NBB, 4096.f*144.f, (unsigned long long)OFF_BN1);
  hipLaunchKernelGGL(kc_kernel, dim3(NBC), dim3(256), 0, stream, P, ws, ws);
  hipLaunchKernelGGL(kstat_kernel, dim3(16), dim3(256), 0, stream, ws, ws,
                     (unsigned long long)OFF_ST2, NBC, 4096.f*25.f, (unsigned long long)OFF_BN2);
  hipLaunchKernelGGL(ke_kernel, dim3(NBE), dim3(256), 0, stream, P, ws, ws);
  hipLaunchKernelGGL(kf_kernel, dim3(16),  dim3(256), 0, stream, P, ws, (float*)d_out);
}

// Round 4
// 359.516 us; speedup vs baseline: 1.6358x; 1.0078x over previous
//
#include <hip/hip_runtime.h>
#include <hip/hip_bf16.h>
#include <math.h>

#define DEV __device__ __forceinline__

constexpr int BATCH = 4096;
constexpr int NBA = 512;    // pool/minmax blocks
constexpr int NBB = 1024;   // conv1-stats blocks (4 img each)
constexpr int NBC = 4096;   // fused conv blocks (1 img each)
constexpr int NBE = 1024;   // fc1 blocks (4 img each)

// workspace layout (float offsets)
constexpr size_t OFF_POOLED = 0;                            // 4096*196
constexpr size_t OFF_Y2P = OFF_POOLED + (size_t)BATCH*196;  // 4096*400 (pooled conv2 out)
constexpr size_t OFF_H3  = OFF_Y2P + (size_t)BATCH*400;     // 4096*128 (fc1 post-relu)
constexpr size_t OFF_ST2 = OFF_H3;                          // 16*NBC*4 = 262144, consumed by kstat2 BEFORE ke writes H3
constexpr size_t OFF_W1  = OFF_H3 + (size_t)BATCH*128;      // 576
constexpr size_t OFF_W2  = OFF_W1 + 576;                    // holds W2 as bf16 hi[9216]+lo[9216] ushorts, [oc][kykx*64+ic]
constexpr size_t OFF_W3  = OFF_W2 + 9216;                   // 51200, layout [k*128+oc]
constexpr size_t OFF_W4  = OFF_W3 + 51200;                  // 1280, natural [oc*128+k]
constexpr size_t OFF_WSC = OFF_W4 + 1280;                   // 4 layer scales
constexpr size_t OFF_MMA = OFF_WSC + 4;                     // NBA*2 pooled min/max partials
constexpr size_t OFF_ST1 = OFF_MMA + (size_t)NBA*2;         // 64*NBB*4 conv1 channel stats partials
constexpr size_t OFF_BN1 = OFF_ST1 + (size_t)64*NBB*4;      // 64*4 {mean, sd, tmin, tmax}
constexpr size_t OFF_BN2 = OFF_BN1 + 256;                   // 16*4
constexpr size_t OFF_MME = OFF_BN2 + 64;                    // NBE*2 fc1 min/max partials

typedef __attribute__((ext_vector_type(8))) short bf16x8;
typedef __attribute__((ext_vector_type(4))) float f32x4;

struct InPtrs {
  const float* x;
  const float* sc[4];
  const float* sg[4];
  const float* on[4];
  const float* ze[4];
  const int* qb;
};

DEV unsigned fenc(float f){ unsigned u=__float_as_uint(f); return (u&0x80000000u)? ~u : (u|0x80000000u); }
DEV float fdec(unsigned e){ return __uint_as_float((e&0x80000000u)? (e&0x7fffffffu) : ~e); }
// fp32 -> bf16 bits, round-to-nearest-even
DEV unsigned short f2bf(float f){ unsigned u=__float_as_uint(f); return (unsigned short)((u + 0x7fffu + ((u>>16)&1u))>>16); }

DEV float blk_min(float v, float* red, int t){
  red[t]=v; __syncthreads();
  for (int s=128;s>0;s>>=1){ if(t<s) red[t]=fminf(red[t],red[t+s]); __syncthreads(); }
  float r=red[0]; __syncthreads();
  return r;
}
DEV float blk_max(float v, float* red, int t){
  red[t]=v; __syncthreads();
  for (int s=128;s>0;s>>=1){ if(t<s) red[t]=fmaxf(red[t],red[t+s]); __syncthreads(); }
  float r=red[0]; __syncthreads();
  return r;
}
DEV float blk_sum(float v, float* red, int t){
  red[t]=v; __syncthreads();
  for (int s=128;s>0;s>>=1){ if(t<s) red[t]+=red[t+s]; __syncthreads(); }
  float r=red[0]; __syncthreads();
  return r;
}

DEV void loadrow16(const float* p, float* r){
  const float4* q=(const float4*)p;
  float4 a=q[0],b=q[1],c=q[2],d=q[3];
  r[0]=a.x;r[1]=a.y;r[2]=a.z;r[3]=a.w;
  r[4]=b.x;r[5]=b.y;r[6]=b.z;r[7]=b.w;
  r[8]=c.x;r[9]=c.y;r[10]=c.z;r[11]=c.w;
  r[12]=d.x;r[13]=d.y;r[14]=d.z;r[15]=d.w;
}

DEV float conv9(const float* ra,const float* rb,const float* rc,const float* w,int x){
  float a=ra[x]*w[0];
  a=fmaf(ra[x+1],w[1],a); a=fmaf(ra[x+2],w[2],a);
  a=fmaf(rb[x],w[3],a);   a=fmaf(rb[x+1],w[4],a); a=fmaf(rb[x+2],w[5],a);
  a=fmaf(rc[x],w[6],a);   a=fmaf(rc[x+1],w[7],a); a=fmaf(rc[x+2],w[8],a);
  return a;
}

// one 12-wide conv1 output row -> channel stats (v = conv/scale1w)
DEV void c1row_stat(const float* ra,const float* rb,const float* rc,const float* w,
                    float inv_s1w,float& sum,float& sq,float& vmn,float& vmx){
  #pragma unroll
  for (int x=0;x<12;++x){
    float v=conv9(ra,rb,rc,w,x)*inv_s1w;
    sum+=v; sq=fmaf(v,v,sq); vmn=fminf(vmn,v); vmx=fmaxf(vmx,v);
  }
}

// one 12-wide conv1 row, ONE channel -> bn+relu+quant -> bf16 code ushort in LDS [cell][72]+ch
DEV void c1row1(const float* ra,const float* rb,const float* rc,const float* w,
                float Ac,float Bc,float inv_s2,float lvf,int y,int ch,unsigned short* actA){
  #pragma unroll
  for (int x=0;x<12;++x){
    float a=conv9(ra,rb,rc,w,x);
    float f=fminf(rintf(fmaxf(fmaf(a,Ac,Bc),0.f)*inv_s2),lvf);  // integer 0..255, exact in bf16
    actA[(y*12+x)*72+ch]=(unsigned short)(__float_as_uint(f)>>16);
  }
}

// ---------------- KW: blended weights via exact radix-select top-k of |scores| ----------------
DEV int2 find_hist(const int* hist, int nbins, int kk, int t, int* suf, int* sh2){
  const int G=(nbins+1023)>>10;
  const int lo=t*G, hi=(lo+G<nbins)?(lo+G):nbins;
  int g=0;
  for (int b=lo;b<hi;++b) g+=hist[b];
  suf[t]=g; __syncthreads();
  #pragma unroll
  for (int s=1;s<1024;s<<=1){
    int add=(t+s<1024)?suf[t+s]:0;
    __syncthreads();
    suf[t]+=add;
    __syncthreads();
  }
  const int S=suf[t];
  const int Snext=(t<1023)?suf[t+1]:0;
  if (S>=kk && Snext<kk){
    int c2=Snext;
    for (int b=hi-1;b>=lo;--b){
      c2+=hist[b];
      if (c2>=kk){ sh2[0]=b; sh2[1]=kk-(c2-hist[b]); break; }
    }
  }
  __syncthreads();
  int2 r=make_int2(sh2[0],sh2[1]);
  __syncthreads();
  return r;
}

__global__ __launch_bounds__(1024) void kw_kernel(InPtrs in, float* __restrict__ ws){
  const int t=threadIdx.x;
  const int L=blockIdx.x;
  const int Ns[4]={576,9216,51200,1280};
  const int fans[4]={9,576,400,128};
  const int N=Ns[L];
  const int n4=N>>2;
  const int K=N>>1;
  const float4* sc4=(const float4*)in.sc[L];
  __shared__ int hist[4096];
  __shared__ int suf[1024];
  __shared__ int sh2[2];

  for (int i=t;i<4096;i+=1024) hist[i]=0;
  __syncthreads();
  for (int i=t;i<n4;i+=1024){
    float4 v=sc4[i];
    atomicAdd(&hist[(__float_as_uint(v.x)&0x7fffffffu)>>19],1);
    atomicAdd(&hist[(__float_as_uint(v.y)&0x7fffffffu)>>19],1);
    atomicAdd(&hist[(__float_as_uint(v.z)&0x7fffffffu)>>19],1);
    atomicAdd(&hist[(__float_as_uint(v.w)&0x7fffffffu)>>19],1);
  }
  __syncthreads();
  int2 f1=find_hist(hist,4096,K,t,suf,sh2);
  const unsigned b0=(unsigned)f1.x; const int r1=f1.y;

  for (int i=t;i<4096;i+=1024) hist[i]=0;
  __syncthreads();
  for (int i=t;i<n4;i+=1024){
    float4 v=sc4[i];
    unsigned ux=__float_as_uint(v.x)&0x7fffffffu;
    unsigned uy=__float_as_uint(v.y)&0x7fffffffu;
    unsigned uz=__float_as_uint(v.z)&0x7fffffffu;
    unsigned uw=__float_as_uint(v.w)&0x7fffffffu;
    if ((ux>>19)==b0) atomicAdd(&hist[(ux>>7)&0xfffu],1);
    if ((uy>>19)==b0) atomicAdd(&hist[(uy>>7)&0xfffu],1);
    if ((uz>>19)==b0) atomicAdd(&hist[(uz>>7)&0xfffu],1);
    if ((uw>>19)==b0) atomicAdd(&hist[(uw>>7)&0xfffu],1);
  }
  __syncthreads();
  int2 f2=find_hist(hist,4096,r1,t,suf,sh2);
  const unsigned b1=(unsigned)f2.x; const int r2=f2.y;
  const unsigned pre=(b0<<12)|b1;

  if (t<128) hist[t]=0;
  __syncthreads();
  for (int i=t;i<n4;i+=1024){
    float4 v=sc4[i];
    unsigned ux=__float_as_uint(v.x)&0x7fffffffu;
    unsigned uy=__float_as_uint(v.y)&0x7fffffffu;
    unsigned uz=__float_as_uint(v.z)&0x7fffffffu;
    unsigned uw=__float_as_uint(v.w)&0x7fffffffu;
    if ((ux>>7)==pre) atomicAdd(&hist[ux&127u],1);
    if ((uy>>7)==pre) atomicAdd(&hist[uy&127u],1);
    if ((uz>>7)==pre) atomicAdd(&hist[uz&127u],1);
    if ((uw>>7)==pre) atomicAdd(&hist[uw&127u],1);
  }
  __syncthreads();
  int2 f3=find_hist(hist,128,r2,t,suf,sh2);
  const unsigned T=(pre<<7)|(unsigned)f3.x;  // bits of k-th largest |score|

  const float4* sg4=(const float4*)in.sg[L];
  const float4* on4=(const float4*)in.on[L];
  const float4* ze4=(const float4*)in.ze[L];
  float* wout=ws+(L==0?OFF_W1: L==2?OFF_W3 : OFF_W4);
  unsigned short* W2H=(unsigned short*)(ws+OFF_W2);
  unsigned short* W2L=W2H+9216;
  double lsum=0.0;
  for (int i4=t;i4<n4;i4+=1024){
    float4 s=sc4[i4], g=sg4[i4], o=on4[i4], z=ze4[i4];
    float sv[4]={s.x,s.y,s.z,s.w}, gv[4]={g.x,g.y,g.z,g.w};
    float ov[4]={o.x,o.y,o.z,o.w}, zv[4]={z.x,z.y,z.z,z.w};
    #pragma unroll
    for (int j=0;j<4;++j){
      int i=i4*4+j;
      unsigned u=__float_as_uint(sv[j])&0x7fffffffu;
      float w=gv[j]*((u>=T)? ov[j] : zv[j]);
      if (L==1){
        int oc=i/576; int r=i-oc*576; int ic=r/9; int kp=r-ic*9;
        int o2=oc*576 + kp*64 + ic;
        unsigned short hb=f2bf(w);
        float lo=w-__uint_as_float((unsigned)hb<<16);
        W2H[o2]=hb; W2L[o2]=f2bf(lo);
      } else {
        int o2;
        if (L==0) o2=i;
        else if (L==2){ int oc=i/400; int kk=i-oc*400; o2=kk*128+oc; }
        else o2=i;
        wout[o2]=w;
      }
      lsum+=(double)ov[j];
    }
  }
  __shared__ double dred[1024];
  dred[t]=lsum; __syncthreads();
  for (int s=512;s>0;s>>=1){ if(t<s) dred[t]+=dred[t+s]; __syncthreads(); }
  if (t==0) ws[OFF_WSC+L]=(float)((dred[0]/(double)N)*sqrt((double)fans[L])*0.5);
}

// ---------------- KA: 2x2 maxpool + pooled min/max partials ----------------
__global__ __launch_bounds__(256) void ka_kernel(InPtrs in, float* __restrict__ ws){
  const int t=threadIdx.x, blk=blockIdx.x;
  const float* x=in.x;
  float* pooled=ws+OFF_POOLED;
  float lmn=3.4e38f, lmx=-3.4e38f;
  for (int p=blk*256+t; p<BATCH*196; p+=NBA*256){
    int b=p/196, r=p-b*196;
    int oy=r/14, ox=r-oy*14;
    const float* px=x+b*784+oy*56+ox*2;
    float m=fmaxf(fmaxf(px[0],px[1]),fmaxf(px[28],px[29]));
    pooled[p]=m;
    lmn=fminf(lmn,m); lmx=fmaxf(lmx,m);
  }
  __shared__ float red[256];
  float bmn=blk_min(lmn,red,t);
  float bmx=blk_max(lmx,red,t);
  if (t==0){ ws[OFF_MMA+blk*2]=bmn; ws[OFF_MMA+blk*2+1]=bmx; }
}

// ---------------- KB: conv1 (recomputed, 4 img/block) -> per-channel BN1 stats partials ----------------
__global__ __launch_bounds__(256) void kb_kernel(InPtrs in, const float* __restrict__ wsr, float* __restrict__ wsw){
  const int t=threadIdx.x, blk=blockIdx.x;
  __shared__ __align__(16) float qxs[224];
  __shared__ float red[256];
  const float* pooled=wsr+OFF_POOLED;
  float lmn=3.4e38f,lmx=-3.4e38f;
  for (int i=t;i<NBA;i+=256){ lmn=fminf(lmn,wsr[OFF_MMA+2*i]); lmx=fmaxf(lmx,wsr[OFF_MMA+2*i+1]); }
  const float mn0=blk_min(lmn,red,t);
  const float mx0=blk_max(lmx,red,t);
  const float lvf=(float)((1<<in.qb[0])-1);
  const float s0=(mx0-mn0)/lvf;
  const float inv_s0=1.0f/s0;
  const float zp0=floorf(mn0/s0);
  const float inv_s1w=1.0f/wsr[OFF_WSC+0];
  const int c=t>>2, q=t&3;
  float w[9];
  #pragma unroll
  for (int j=0;j<9;++j) w[j]=wsr[OFF_W1+c*9+j];
  float sum=0.f,sq=0.f,vmn=3.4e38f,vmx=-3.4e38f;
  #pragma unroll 1
  for (int ii=0;ii<4;++ii){
    const int b=blk*4+ii;
    __syncthreads();
    for (int i=t;i<224;i+=256){
      int row=i>>4,col=i&15;
      float v=0.f;
      if (col<14){ float xx=pooled[b*196+row*14+col]; v=(rintf((xx-mn0)*inv_s0)+zp0)*s0; }
      qxs[i]=v;
    }
    __syncthreads();
    float rA[16],rB[16],rC[16];
    const int y0=q*3;
    loadrow16(qxs+y0*16,rA);
    loadrow16(qxs+(y0+1)*16,rB);
    loadrow16(qxs+(y0+2)*16,rC); c1row_stat(rA,rB,rC,w,inv_s1w,sum,sq,vmn,vmx);
    loadrow16(qxs+(y0+3)*16,rA); c1row_stat(rB,rC,rA,w,inv_s1w,sum,sq,vmn,vmx);
    loadrow16(qxs+(y0+4)*16,rB); c1row_stat(rC,rA,rB,w,inv_s1w,sum,sq,vmn,vmx);
  }
  #pragma unroll
  for (int d=1;d<4;d<<=1){
    sum+=__shfl_xor(sum,d);
    sq +=__shfl_xor(sq,d);
    vmn=fminf(vmn,__shfl_xor(vmn,d));
    vmx=fmaxf(vmx,__shfl_xor(vmx,d));
  }
  if (q==0){
    float* p=wsw+OFF_ST1+((size_t)c*NBB+blk)*4;
    p[0]=sum; p[1]=sq; p[2]=vmn; p[3]=vmx;
  }
}

// ---------------- kstat: per-channel partial reduce -> {mean, sd, tmin, tmax} ----------------
__global__ __launch_bounds__(256) void kstat_kernel(const float* __restrict__ wsr, float* __restrict__ wsw,
                                                    unsigned long long inoff, int nparts, float Nf,
                                                    unsigned long long outoff){
  const int c=blockIdx.x, t=threadIdx.x;
  __shared__ float red[256];
  const float* p=wsr+inoff+(size_t)c*nparts*4;
  float sum=0.f,sq=0.f,mn=3.4e38f,mx=-3.4e38f;
  for (int i=t;i<nparts;i+=256){
    sum+=p[i*4]; sq+=p[i*4+1];
    mn=fminf(mn,p[i*4+2]); mx=fmaxf(mx,p[i*4+3]);
  }
  float S=blk_sum(sum,red,t);
  float Q=blk_sum(sq,red,t);
  float MN=blk_min(mn,red,t);
  float MX=blk_max(mx,red,t);
  if (t==0){
    float mean=S/Nf;
    float var=fmaxf(Q/Nf-mean*mean,0.f);
    float sd=sqrtf(var+1e-5f);
    float* o=wsw+outoff+c*4;
    o[0]=mean; o[1]=sd; o[2]=(MN-mean)/sd; o[3]=(MX-mean)/sd;
  }
}

// ---------------- KC: fused conv1->bn1/relu/quant->conv2(MFMA)->pool, 1 img/block ----------------
__global__ __launch_bounds__(256,6) void kc_kernel(InPtrs in, const float* __restrict__ wsr, float* __restrict__ wsw){
  const int t=threadIdx.x, blk=blockIdx.x;
  __shared__ __align__(16) float qxs[224];              // 14x16 quantized input
  __shared__ __align__(16) unsigned short actA[144*72]; // [cell=y*12+x][72: 64 ch + 8 pad] bf16 codes (20.7 KB)
  float* c2s=(float*)actA;                              // aliased after barrier: [oc][100] conv2 out (6.4 KB)
  __shared__ float sA[64], sB[64];
  __shared__ float red[256];
  __shared__ float stsum[16], stsq[16];
  __shared__ unsigned stmn[16], stmx[16];
  const float* pooled=wsr+OFF_POOLED;
  float lmn=3.4e38f,lmx=-3.4e38f;
  for (int i=t;i<NBA;i+=256){ lmn=fminf(lmn,wsr[OFF_MMA+2*i]); lmx=fmaxf(lmx,wsr[OFF_MMA+2*i+1]); }
  const float mn0=blk_min(lmn,red,t);
  const float mx0=blk_max(lmx,red,t);
  const float lvf=(float)((1<<in.qb[0])-1);
  const float s0=(mx0-mn0)/lvf, inv_s0=1.0f/s0, zp0=floorf(mn0/s0);
  const float s1w=wsr[OFF_WSC+0], s2w=wsr[OFF_WSC+1];
  if (t<64){
    float m=wsr[OFF_BN1+t*4], sd=wsr[OFF_BN1+t*4+1];
    sA[t]=1.0f/(s1w*sd);
    sB[t]=-m/sd;
  }
  float tmn=(t<64)?wsr[OFF_BN1+t*4+2]:3.4e38f;
  float tmx=(t<64)?wsr[OFF_BN1+t*4+3]:-3.4e38f;
  const float rmn=blk_min(tmn,red,t);
  const float rmx=blk_max(tmx,red,t);
  const float s2=(fmaxf(rmx,0.f)-fmaxf(rmn,0.f))/lvf;
  const float inv_s2=1.0f/s2;
  const float g2=s2/s2w;
  if (t<16){ stsum[t]=0.f; stsq[t]=0.f; stmn[t]=0xFFFFFFFFu; stmx[t]=0u; }
  __syncthreads();

  // quantized pooled input
  if (t<224){
    int row=t>>4, col=t&15;
    float v=0.f;
    if (col<14){ float xx=pooled[blk*196+row*14+col]; v=(rintf((xx-mn0)*inv_s0)+zp0)*s0; }
    qxs[t]=v;
  }
  __syncthreads();

  // conv1 + bn + relu + quant -> bf16 codes; wave = one part (3 rows), lane = channel
  {
    const int part=t>>6, ch=t&63;
    const float Ac=sA[ch], Bc=sB[ch];
    float w[9];
    #pragma unroll
    for (int j=0;j<9;++j) w[j]=wsr[OFF_W1+ch*9+j];
    float rA[16],rB[16],rC[16];
    const int y0=part*3;
    loadrow16(qxs+y0*16,rA);
    loadrow16(qxs+(y0+1)*16,rB);
    loadrow16(qxs+(y0+2)*16,rC); c1row1(rA,rB,rC,w,Ac,Bc,inv_s2,lvf,y0+0,ch,actA);
    loadrow16(qxs+(y0+3)*16,rA); c1row1(rB,rC,rA,w,Ac,Bc,inv_s2,lvf,y0+1,ch,actA);
    loadrow16(qxs+(y0+4)*16,rB); c1row1(rC,rA,rB,w,Ac,Bc,inv_s2,lvf,y0+2,ch,actA);
  }
  __syncthreads();

  // conv2 via MFMA: 7 M-tiles of 16 positions; wave w gets tau=w, w+4
  {
    const int w=t>>6, lane=t&63;
    const int oc=lane&15, quad=lane>>4;
    const unsigned short* W2H=(const unsigned short*)(wsr+OFF_W2);
    const unsigned short* W2L=W2H+9216;
    const int boff=oc*576+quad*8;

    const int nT=(w<3)?2:1;
    int abase[2]; int taus[2];
    for (int i=0;i<nT;++i){
      int tau=w+i*4;
      int posb=tau*16+(lane&15);
      int pc=posb>99?99:posb;
      int py=pc/10, px=pc-py*10;
      abase[i]=(py*12+px)*72+quad*8;
      taus[i]=tau;
    }
    f32x4 acc[2];
    acc[0]=(f32x4){0.f,0.f,0.f,0.f};
    acc[1]=(f32x4){0.f,0.f,0.f,0.f};

    #pragma unroll 1
    for (int kykx=0;kykx<9;++kykx){
      const int kb=kykx*64;
      const int co=((kykx/3)*12+(kykx%3))*72;
      #pragma unroll
      for (int s=0;s<2;++s){
        bf16x8 bh=*(const bf16x8*)(W2H+boff+kb+s*32);
        bf16x8 bl=*(const bf16x8*)(W2L+boff+kb+s*32);
        #pragma unroll
        for (int i=0;i<2;++i){
          if (i<nT){
            bf16x8 a=*(const bf16x8*)(actA+abase[i]+co+s*32);
            acc[i]=__builtin_amdgcn_mfma_f32_16x16x32_bf16(a,bh,acc[i],0,0,0);
            acc[i]=__builtin_amdgcn_mfma_f32_16x16x32_bf16(a,bl,acc[i],0,0,0);
          }
        }
      }
    }
    __syncthreads();   // all actA reads done before aliased c2s writes
    // C layout: col(oc)=lane&15, row(pos-in-tile)=quad*4+reg
    for (int i=0;i<nT;++i){
      int pos4=taus[i]*16+quad*4;
      if (pos4<100){
        float4* dst=(float4*)&c2s[oc*100+pos4];
        *dst=make_float4(acc[i].x*g2,acc[i].y*g2,acc[i].z*g2,acc[i].w*g2);
      }
    }
  }
  __syncthreads();

  // 2x2 maxpool + per-channel stats
  for (int i=t;i<400;i+=256){
    int ch=i/25, pp=i-ch*25;
    int py=pp/5, px=pp-py*5;
    const float* cc=c2s+ch*100;
    int base=py*20+px*2;
    float v=fmaxf(fmaxf(cc[base],cc[base+1]),fmaxf(cc[base+10],cc[base+11]));
    wsw[OFF_Y2P+(size_t)blk*400+i]=v;
    atomicAdd(&stsum[ch],v);
    atomicAdd(&stsq[ch],v*v);
    atomicMin(&stmn[ch],fenc(v));
    atomicMax(&stmx[ch],fenc(v));
  }
  __syncthreads();
  if (t<16){
    float* p=wsw+OFF_ST2+((size_t)t*NBC+blk)*4;
    p[0]=stsum[t]; p[1]=stsq[t]; p[2]=fdec(stmn[t]); p[3]=fdec(stmx[t]);
  }
}

// ---------------- KE: bn2/relu/quant -> fc1 -> relu, 4 img/block, min/max partials ----------------
__global__ __launch_bounds__(256) void ke_kernel(InPtrs in, const float* __restrict__ wsr, float* __restrict__ wsw){
  const int t=threadIdx.x, blk=blockIdx.x;
  __shared__ float xs[1600];   // 4 img x 400
  __shared__ float red[256];
  __shared__ float sm[16], sisd[16];
  const float lvf=(float)((1<<in.qb[0])-1);
  float tmn=(t<16)?wsr[OFF_BN2+t*4+2]:3.4e38f;
  float tmx=(t<16)?wsr[OFF_BN2+t*4+3]:-3.4e38f;
  if (t<16){ sm[t]=wsr[OFF_BN2+t*4]; sisd[t]=1.0f/wsr[OFF_BN2+t*4+1]; }
  const float rmn=blk_min(tmn,red,t);
  const float rmx=blk_max(tmx,red,t);
  const float s3=(fmaxf(rmx,0.f)-fmaxf(rmn,0.f))/lvf;
  const float inv_s3=1.0f/s3;
  const float inv_s3w=1.0f/wsr[OFF_WSC+2];
  const int b0=blk*4;
  for (int i=t;i<1600;i+=256){
    int img=i/400, k=i-img*400;
    int ch=k/25;
    float y=wsr[OFF_Y2P+(size_t)(b0+img)*400+k];
    float bn=(y-sm[ch])*sisd[ch];
    float r=fmaxf(bn,0.f);
    xs[i]=fminf(rintf(r*inv_s3),lvf)*s3;
  }
  __syncthreads();
  const int iml=t>>6, lane=t&63;
  const float* xr=xs+iml*400;
  const float* w3=wsr+OFF_W3;
  float a0=0.f,a1=0.f;
  #pragma unroll 4
  for (int k=0;k<400;++k){
    float xv=xr[k];
    const float2* wp=(const float2*)(w3+k*128+lane*2);
    float2 wv=*wp;
    a0=fmaf(xv,wv.x,a0); a1=fmaf(xv,wv.y,a1);
  }
  float h0=fmaxf(a0*inv_s3w,0.f);
  float h1=fmaxf(a1*inv_s3w,0.f);
  float* hp=wsw+OFF_H3+(size_t)(b0+iml)*128+lane*2;
  hp[0]=h0; hp[1]=h1;
  float hmn=fminf(h0,h1), hmx=fmaxf(h0,h1);
  float bmn=blk_min(hmn,red,t);
  float bmx=blk_max(hmx,red,t);
  if (t==0){ wsw[OFF_MME+blk*2]=bmn; wsw[OFF_MME+blk*2+1]=bmx; }
}

// ---------------- KF: quant -> fc2 -> log_softmax; 64 rows/block, 4 lanes/row ----------------
__global__ __launch_bounds__(256) void kf_kernel(InPtrs in, const float* __restrict__ wsr, float* __restrict__ out){
  const int t=threadIdx.x, blk=blockIdx.x;
  __shared__ float red[256];
  __shared__ float w4s[1280];
  const float lvf=(float)((1<<in.qb[0])-1);
  float lmn=3.4e38f,lmx=-3.4e38f;
  for (int i=t;i<NBE;i+=256){ lmn=fminf(lmn,wsr[OFF_MME+2*i]); lmx=fmaxf(lmx,wsr[OFF_MME+2*i+1]); }
  for (int i=t;i<1280;i+=256) w4s[i]=wsr[OFF_W4+i];
  const float hmn=blk_min(lmn,red,t);
  const float hmx=blk_max(lmx,red,t);
  const float s4=(hmx-hmn)/lvf;
  const float inv_s4=1.0f/s4;
  const float inv_s4w=1.0f/wsr[OFF_WSC+3];
  const int row=blk*64+(t>>2), l4=t&3;
  const float4* hr4=(const float4*)(wsr+OFF_H3+(size_t)row*128);
  float acc[10];
  #pragma unroll
  for (int j=0;j<10;++j) acc[j]=0.f;
  #pragma unroll 2
  for (int j=0;j<8;++j){
    float4 v=hr4[l4*8+j];
    int kb=(l4*8+j)*4;
    float q0=fminf(rintf(v.x*inv_s4),lvf)*s4;
    float q1=fminf(rintf(v.y*inv_s4),lvf)*s4;
    float q2=fminf(rintf(v.z*inv_s4),lvf)*s4;
    float q3=fminf(rintf(v.w*inv_s4),lvf)*s4;
    #pragma unroll
    for (int o=0;o<10;++o){
      const float* wr=w4s+o*128+kb;
      acc[o]=fmaf(q0,wr[0],acc[o]);
      acc[o]=fmaf(q1,wr[1],acc[o]);
      acc[o]=fmaf(q2,wr[2],acc[o]);
      acc[o]=fmaf(q3,wr[3],acc[o]);
    }
  }
  #pragma unroll
  for (int o=0;o<10;++o){
    acc[o]+=__shfl_xor(acc[o],1);
    acc[o]+=__shfl_xor(acc[o],2);
  }
  if (l4==0){
    float mx=-3.4e38f;
    #pragma unroll
    for (int o=0;o<10;++o){ acc[o]*=inv_s4w; mx=fmaxf(mx,acc[o]); }
    float se=0.f;
    #pragma unroll
    for (int o=0;o<10;++o) se+=expf(acc[o]-mx);
    const float ls=logf(se);
    #pragma unroll
    for (int o=0;o<10;++o) out[row*10+o]=acc[o]-mx-ls;
  }
}

extern "C" void kernel_launch(void* const* d_in, const int* in_sizes, int n_in,
                              void* d_out, int out_size, void* d_ws, size_t ws_size,
                              hipStream_t stream){
  (void)in_sizes; (void)n_in; (void)out_size; (void)ws_size;
  InPtrs P;
  P.x=(const float*)d_in[0];
  for (int l=0;l<4;++l){
    P.sc[l]=(const float*)d_in[1+l*4];
    P.sg[l]=(const float*)d_in[2+l*4];
    P.on[l]=(const float*)d_in[3+l*4];
    P.ze[l]=(const float*)d_in[4+l*4];
  }
  P.qb=(const int*)d_in[17];
  float* ws=(float*)d_ws;

  hipLaunchKernelGGL(kw_kernel, dim3(4),   dim3(1024), 0, stream, P, ws);
  hipLaunchKernelGGL(ka_kernel, dim3(NBA), dim3(256), 0, stream, P, ws);
  hipLaunchKernelGGL(kb_kernel, dim3(NBB), dim3(256), 0, stream, P, ws, ws);
  hipLaunchKernelGGL(kstat_kernel, dim3(64), dim3(256), 0, stream, ws, ws,
                     (unsigned long long)OFF_ST1, NBB, 4096.f*144.f, (unsigned long long)OFF_BN1);
  hipLaunchKernelGGL(kc_kernel, dim3(NBC), dim3(256), 0, stream, P, ws, ws);
  hipLaunchKernelGGL(kstat_kernel, dim3(16), dim3(256), 0, stream, ws, ws,
                     (unsigned long long)OFF_ST2, NBC, 4096.f*25.f, (unsigned long long)OFF_BN2);
  hipLaunchKernelGGL(ke_kernel, dim3(NBE), dim3(256), 0, stream, P, ws, ws);
  hipLaunchKernelGGL(kf_kernel, dim3(64),  dim3(256), 0, stream, P, ws, (float*)d_out);
}